// Round 9
// baseline (447.012 us; speedup 1.0000x reference)
//
#include <hip/hip_runtime.h>
#include <hip/hip_bf16.h>

#define BB 4
#define TT 1024
#define DM 1024
#define HH 16

typedef __attribute__((ext_vector_type(8))) short short8;
typedef __attribute__((ext_vector_type(4))) short short4v;
typedef __attribute__((ext_vector_type(4))) float f32x4;
typedef __hip_bfloat16 bf16;

__device__ __forceinline__ f32x4 mfma16(short8 a, short8 b, f32x4 c) {
  return __builtin_amdgcn_mfma_f32_16x16x32_bf16(a, b, c, 0, 0, 0);
}

// ---------------------------------------------------------------------------
// x fp32 -> bf16, 8 elems/thread. grid 2048.
// ---------------------------------------------------------------------------
__global__ __launch_bounds__(256) void xb_kernel(
    const float* __restrict__ x, bf16* __restrict__ xb) {
  const size_t i = ((size_t)blockIdx.x * 256 + threadIdx.x) * 8;
  bf16 tmp[8];
#pragma unroll
  for (int j = 0; j < 8; ++j) tmp[j] = __float2bfloat16(x[i + j]);
  *(short8*)(xb + i) = *(const short8*)tmp;
}

// ---------------------------------------------------------------------------
// W_{Q,K,V} fp32 [16][64 d][64 e] -> Wt bf16 [3][16][64 e][64 d] (transposed)
// grid (16 h, 3 m)
// ---------------------------------------------------------------------------
__global__ __launch_bounds__(256) void prep_w_kernel(
    const float* __restrict__ WQ, const float* __restrict__ WK,
    const float* __restrict__ WV, bf16* __restrict__ Wt) {
  __shared__ bf16 tl[64][72];
  const int h = blockIdx.x, m = blockIdx.y;
  const float* W = (m == 0 ? WQ : (m == 1 ? WK : WV)) + h * 4096;
  const int tid = threadIdx.x;
  const int r = tid >> 2, c = (tid & 3) * 16;
#pragma unroll
  for (int i = 0; i < 16; ++i)
    tl[r][c + i] = __float2bfloat16(W[r * 64 + c + i]);  // tl[d][e]
  __syncthreads();
  bf16* o = Wt + ((size_t)(m * 16 + h) * 64 + r) * 64 + c;  // [e=r][d=c..]
#pragma unroll
  for (int i = 0; i < 16; ++i) o[i] = tl[c + i][r];
}

// ---------------------------------------------------------------------------
// prep: posK fp32 [2047][64] -> bf16 [2048][64] (row 2047 zeroed)
// ---------------------------------------------------------------------------
__global__ __launch_bounds__(256) void prep_posk_kernel(
    const float* __restrict__ posK, bf16* __restrict__ posKbf) {
  const int idx = blockIdx.x * 256 + threadIdx.x;
  const int p = idx >> 6, d = idx & 63;
  const float v = (p < 2047) ? posK[(size_t)p * 64 + d] : 0.f;
  posKbf[idx] = __float2bfloat16(v);
}

// ---------------------------------------------------------------------------
// prep: WzT bf16 [n][k] = Wz fp32 [k][n]
// ---------------------------------------------------------------------------
__global__ __launch_bounds__(256) void trans_wz_kernel(
    const float* __restrict__ Wz, bf16* __restrict__ WzT) {
  __shared__ bf16 tile[64][72];
  const int k0 = blockIdx.y * 64, n0 = blockIdx.x * 64;
  const int tid = threadIdx.x;
  const int r = tid >> 2, c = (tid & 3) * 16;
  const float* s = Wz + (size_t)(k0 + r) * 1024 + n0 + c;
#pragma unroll
  for (int i = 0; i < 16; ++i) tile[r][c + i] = __float2bfloat16(s[i]);
  __syncthreads();
  const int n = tid >> 2;
  bf16* o = WzT + (size_t)(n0 + n) * 1024 + k0 + c;
#pragma unroll
  for (int i = 0; i < 16; ++i) o[i] = tile[c + i][n];
}

// ---------------------------------------------------------------------------
// transpose V: [bh][1024][64] bf16 -> Vt [bh][64][1024] bf16
// ---------------------------------------------------------------------------
__global__ __launch_bounds__(256) void trans_v_kernel(
    const bf16* __restrict__ src, bf16* __restrict__ dst) {
  __shared__ bf16 tile[64][72];
  const int bh = blockIdx.y, t0 = blockIdx.x * 64;
  const int tid = threadIdx.x;
  const int r = tid >> 2, c = (tid & 3) * 16;
  const bf16* s = src + ((size_t)bh * TT + t0 + r) * 64 + c;
  *(short8*)(&tile[r][c]) = *(const short8*)(s);
  *(short8*)(&tile[r][c + 8]) = *(const short8*)(s + 8);
  __syncthreads();
  const int d = tid >> 2;
  bf16* o = dst + ((size_t)bh * 64 + d) * TT + t0 + c;
#pragma unroll
  for (int i = 0; i < 16; ++i) o[i] = tile[c + i][d];
}

// ---------------------------------------------------------------------------
// QKV projection via MFMA. grid (16 ttiles, 64 bh), block 256 (4 waves).
// ---------------------------------------------------------------------------
__global__ __launch_bounds__(256) void qkv_mfma_kernel(
    const bf16* __restrict__ xb, const bf16* __restrict__ Wt,
    bf16* __restrict__ Qg, bf16* __restrict__ Kg, bf16* __restrict__ Vg) {
  __shared__ __align__(16) bf16 xs[64 * 72];
  const int bh = blockIdx.y;
  const int b = bh >> 4, h = bh & 15;
  const int t0 = blockIdx.x * 64;
  const int tid = threadIdx.x;
  const int w = tid >> 6, lane = tid & 63, l15 = lane & 15, hi = lane >> 4;

  {
    const int r = tid >> 2, c = (tid & 3) * 16;
    const bf16* src = xb + ((size_t)b * TT + t0 + r) * DM + h * 64 + c;
    *(short8*)(xs + r * 72 + c) = *(const short8*)(src);
    *(short8*)(xs + r * 72 + c + 8) = *(const short8*)(src + 8);
  }
  __syncthreads();

  f32x4 aQ[4] = {{0.f, 0.f, 0.f, 0.f}, {0.f, 0.f, 0.f, 0.f},
                 {0.f, 0.f, 0.f, 0.f}, {0.f, 0.f, 0.f, 0.f}};
  f32x4 aK[4] = {{0.f, 0.f, 0.f, 0.f}, {0.f, 0.f, 0.f, 0.f},
                 {0.f, 0.f, 0.f, 0.f}, {0.f, 0.f, 0.f, 0.f}};
  f32x4 aV[4] = {{0.f, 0.f, 0.f, 0.f}, {0.f, 0.f, 0.f, 0.f},
                 {0.f, 0.f, 0.f, 0.f}, {0.f, 0.f, 0.f, 0.f}};
  const bf16* WtQ = Wt + (size_t)h * 4096;
  const bf16* WtK = Wt + (size_t)(16 + h) * 4096;
  const bf16* WtV = Wt + (size_t)(32 + h) * 4096;
#pragma unroll
  for (int kc = 0; kc < 2; ++kc) {
    const short8 a =
        *(const short8*)(xs + (w * 16 + l15) * 72 + kc * 32 + hi * 8);
#pragma unroll
    for (int nt = 0; nt < 4; ++nt) {
      const size_t wo = (size_t)(nt * 16 + l15) * 64 + kc * 32 + hi * 8;
      aQ[nt] = mfma16(a, *(const short8*)(WtQ + wo), aQ[nt]);
      aK[nt] = mfma16(a, *(const short8*)(WtK + wo), aK[nt]);
      aV[nt] = mfma16(a, *(const short8*)(WtV + wo), aV[nt]);
    }
  }
  const int t = t0 + w * 16 + hi * 4;
#pragma unroll
  for (int nt = 0; nt < 4; ++nt) {
#pragma unroll
    for (int j = 0; j < 4; ++j) {
      const size_t o = ((size_t)bh * TT + t + j) * 64 + nt * 16 + l15;
      Qg[o] = __float2bfloat16(aQ[nt][j]);
      Kg[o] = __float2bfloat16(aK[nt][j]);
      Vg[o] = __float2bfloat16(aV[nt][j]);
    }
  }
}

// ---------------------------------------------------------------------------
// Fused score kernel v5: SWAPPED QK^T -> barrier-free k-loop.
//  - mfma(K, Q) gives S^T (col=q=l15, row=k=hi*4+reg): P is wave-k-local.
//  - each wave owns a private 32-k window per iteration (8 iters x 4 waves
//    cover 1024 k); P staged in a wave-PRIVATE LDS buffer [16q][32k] in
//    B-frag order -> 1 ds_read_b128 feeds all 4 PV MFMAs; zero barriers.
//  - each wave accumulates ctx^T[d][q] partials over its k-subset; one
//    epilogue with 2 barriers combines waves (ctx and l).
// grid (64 bh, 16 qt), block 256 (4 waves).
// ---------------------------------------------------------------------------
#define QP8_S 2052

__global__ __launch_bounds__(256, 4) void score_pv_kernel(
    const bf16* __restrict__ Qb,
    const bf16* __restrict__ Kb,
    const bf16* __restrict__ posKbf,
    const bf16* __restrict__ Vt,
    const float* __restrict__ maskp,
    const int* __restrict__ pos,
    bf16* __restrict__ Pws,        // [256 qlocal][64 bh][1024 k]
    float* __restrict__ l_ws,      // [64 bh][1024 q]
    float* __restrict__ ctxU,      // [b][t][1024] fp32 unnormalized
    int slab) {
  __shared__ __align__(16) unsigned char QPsh[16 * QP8_S];  // 32832 B
  __shared__ __align__(16) bf16 Psm[4][16 * 32];            // 4096 B (per-wave)
  __shared__ float lred[4][16];                             // 256 B
  float* red = (float*)QPsh;  // epilogue reuse: [4][16][65] fp32 = 16640 B

  const int bh = blockIdx.x;
  const int qt = blockIdx.y;
  const int qlocal0 = qt * 16;
  const int qg0 = slab * 256 + qlocal0;
  const int tid = threadIdx.x;
  const int w = tid >> 6;
  const int lane = tid & 63;
  const int l15 = lane & 15;
  const int hi = lane >> 4;

  // Q fragments: rows q = l15, d-chunks hi*8 / 32+hi*8.
  // Used as A in the QP phase, as B in the swapped QK^T.
  const bf16* Qrow = Qb + ((size_t)bh * TT + qg0 + l15) * 64 + hi * 8;
  const short8 aq0 = *(const short8*)(Qrow);
  const short8 aq1 = *(const short8*)(Qrow + 32);

  // ---- QP phase (unchanged): wave w covers p-tiles w*32..w*32+31; fp8 store
  {
    const bf16* Kp0 = posKbf + ((size_t)(w * 32 * 16 + l15)) * 64 + hi * 8;
    short8 qb0 = *(const short8*)(Kp0);
    short8 qb1 = *(const short8*)(Kp0 + 32);
    for (int i = 0; i < 32; ++i) {
      const int pt = w * 32 + i;
      const short8 cb0 = qb0, cb1 = qb1;
      {
        const int ptn = w * 32 + ((i + 1) & 31);
        const bf16* Kpn = posKbf + ((size_t)(ptn * 16 + l15)) * 64 + hi * 8;
        qb0 = *(const short8*)(Kpn);
        qb1 = *(const short8*)(Kpn + 32);
      }
      f32x4 acc = {0.f, 0.f, 0.f, 0.f};
      acc = mfma16(aq0, cb0, acc);
      acc = mfma16(aq1, cb1, acc);
      const int p01 = __builtin_amdgcn_cvt_pk_fp8_f32(acc[0], acc[1], 0, false);
      const int p23 = __builtin_amdgcn_cvt_pk_fp8_f32(acc[2], acc[3], 0, false);
      const int off = pt * 16 + l15;
      QPsh[(hi * 4 + 0) * QP8_S + off] = (unsigned char)(p01 & 0xff);
      QPsh[(hi * 4 + 1) * QP8_S + off] = (unsigned char)((p01 >> 8) & 0xff);
      QPsh[(hi * 4 + 2) * QP8_S + off] = (unsigned char)(p23 & 0xff);
      QPsh[(hi * 4 + 3) * QP8_S + off] = (unsigned char)((p23 >> 8) & 0xff);
    }
  }
  __syncthreads();

  // ---- barrier-free k-loop
  // acc[nt] holds ctx^T tile: d = nt*16 + hi*4 + reg, q = l15 (wave-partial)
  f32x4 acc[4] = {{0.f, 0.f, 0.f, 0.f}, {0.f, 0.f, 0.f, 0.f},
                  {0.f, 0.f, 0.f, 0.f}, {0.f, 0.f, 0.f, 0.f}};
  float lsum = 0.f;
  bf16* psm = &Psm[w][0];
  const bf16* Kbh = Kb + (size_t)bh * TT * 64;
  const bf16* Vtbh = Vt + (size_t)bh * 64 * TT;
  const size_t qrow_go = (size_t)(qg0 + l15) * TT;

  for (int it = 0; it < 8; ++it) {
    const int kw = it * 128 + w * 32;  // wave-private 32-k window
    // K A-frags: rows k = kw + kt*16 + l15, d-chunks hi*8 / 32+hi*8
    const bf16* kr0 = Kbh + (size_t)(kw + l15) * 64 + hi * 8;
    const bf16* kr1 = Kbh + (size_t)(kw + 16 + l15) * 64 + hi * 8;
    const short8 ka00 = *(const short8*)(kr0);
    const short8 ka01 = *(const short8*)(kr0 + 32);
    const short8 ka10 = *(const short8*)(kr1);
    const short8 ka11 = *(const short8*)(kr1 + 32);
    // Vt A-frags: rows d = nt*16 + l15, k-chunk kw + hi*8
    short8 va[4];
#pragma unroll
    for (int nt = 0; nt < 4; ++nt)
      va[nt] = *(const short8*)(Vtbh + (size_t)(nt * 16 + l15) * TT + kw +
                                hi * 8);
    // pos/mask for (q=l15, k = kw + kt*16 + hi*4 + j)
    int cpos[8];
    float cmask[8];
#pragma unroll
    for (int kt = 0; kt < 2; ++kt)
#pragma unroll
      for (int j = 0; j < 4; ++j) {
        const size_t go = qrow_go + kw + kt * 16 + hi * 4 + j;
        cpos[kt * 4 + j] = pos[go];
        cmask[kt * 4 + j] = maskp[go];
      }
    // swapped QK^T: S^T tiles (col=q=l15, row=k=hi*4+reg)
    f32x4 s0 = {0.f, 0.f, 0.f, 0.f};
    s0 = mfma16(ka00, aq0, s0);
    s0 = mfma16(ka01, aq1, s0);
    f32x4 s1 = {0.f, 0.f, 0.f, 0.f};
    s1 = mfma16(ka10, aq0, s1);
    s1 = mfma16(ka11, aq1, s1);
    // exp + stage P into wave-private LDS in B-frag order [q][chunk][8]
#pragma unroll
    for (int kt = 0; kt < 2; ++kt) {
      const f32x4 sv4 = (kt == 0) ? s0 : s1;
      bf16 pb[4];
#pragma unroll
      for (int j = 0; j < 4; ++j) {
        const float qp = __builtin_amdgcn_cvt_f32_fp8(
            (int)QPsh[l15 * QP8_S + cpos[kt * 4 + j]], 0);
        const float sv = (sv4[j] + qp + cmask[kt * 4 + j]) * 0.125f;
        const float pe = __expf(sv);
        lsum += pe;
        pb[j] = __float2bfloat16(pe);
      }
      *(short4v*)(psm + l15 * 32 + (kt * 2 + (hi >> 1)) * 8 + (hi & 1) * 4) =
          *(const short4v*)pb;
    }
    // PV: one B-frag read serves all 4 d-tiles (same wave; lgkm-ordered)
    const short8 pbf = *(const short8*)(psm + l15 * 32 + hi * 8);
#pragma unroll
    for (int nt = 0; nt < 4; ++nt) acc[nt] = mfma16(va[nt], pbf, acc[nt]);
    // Pws store: contiguous LDS read, 64B-coalesced global rows
    const short8 pw = *(const short8*)(psm + lane * 8);
    *(short8*)(Pws + ((size_t)(qlocal0 + (lane >> 2)) * 64 + bh) * TT + kw +
               (lane & 3) * 8) = pw;
  }

  // ---- epilogue: combine wave partials (2 barriers total)
  lsum += __shfl_xor(lsum, 16);
  lsum += __shfl_xor(lsum, 32);
  __syncthreads();  // all QPsh reads done before red overwrite
  if (hi == 0) lred[w][l15] = lsum;
#pragma unroll
  for (int nt = 0; nt < 4; ++nt)
#pragma unroll
    for (int j = 0; j < 4; ++j)
      red[(w * 16 + l15) * 65 + nt * 16 + hi * 4 + j] = acc[nt][j];
  __syncthreads();
  if (tid < 16) {
    const float l = lred[0][tid] + lred[1][tid] + lred[2][tid] + lred[3][tid];
    l_ws[(size_t)bh * TT + qg0 + tid] = l;
  }
  {
    const int b = bh >> 4, h = bh & 15;
    for (int i = tid; i < 1024; i += 256) {
      const int q = i >> 6, d = i & 63;
      const float v = red[(q)*65 + d] + red[(16 + q) * 65 + d] +
                      red[(32 + q) * 65 + d] + red[(48 + q) * 65 + d];
      ctxU[((size_t)b * TT + qg0 + q) * DM + h * 64 + d] = v;
    }
  }
}

// ---------------------------------------------------------------------------
// PV partial kernel (k-split x4): grid (256 q, 4 ks), block 256.
// ---------------------------------------------------------------------------
#define PVT_S 72
__global__ __launch_bounds__(256) void pv_part_kernel(
    const bf16* __restrict__ Pws,
    const float* __restrict__ posV,
    const int* __restrict__ pos,
    float* __restrict__ PP,   // [4][256][64][64] fp32
    int slab) {
  __shared__ __align__(16) bf16 PVt[2][64 * PVT_S];
  __shared__ unsigned short possh[256];

  const int qlocal = blockIdx.x;
  const int q = slab * 256 + qlocal;
  const int ks = blockIdx.y;
  const int kbase = ks * 256;
  const int tid = threadIdx.x;
  const int w = tid >> 6, lane = tid & 63, l15 = lane & 15, hi = lane >> 4;

  possh[tid] = (unsigned short)pos[(size_t)q * TT + kbase + tid];
  __syncthreads();

  f32x4 acc[4] = {{0.f, 0.f, 0.f, 0.f}, {0.f, 0.f, 0.f, 0.f},
                  {0.f, 0.f, 0.f, 0.f}, {0.f, 0.f, 0.f, 0.f}};
  const bf16* Prow = Pws + ((size_t)qlocal * 64 + w * 16 + l15) * TT;

  for (int it = 0; it < 4; ++it) {
    const int k0 = kbase + it * 64;
    bf16* pvt = &PVt[it & 1][0];
    {
      const int kr = lane;
      const int dc = w * 16;
      const int p = possh[it * 64 + kr];
      const float* src = posV + (size_t)p * 64 + dc;
#pragma unroll
      for (int ii = 0; ii < 16; ii += 4) {
        const f32x4 v = *(const f32x4*)(src + ii);
        pvt[(dc + ii + 0) * PVT_S + kr] = __float2bfloat16(v[0]);
        pvt[(dc + ii + 1) * PVT_S + kr] = __float2bfloat16(v[1]);
        pvt[(dc + ii + 2) * PVT_S + kr] = __float2bfloat16(v[2]);
        pvt[(dc + ii + 3) * PVT_S + kr] = __float2bfloat16(v[3]);
      }
    }
    __syncthreads();
#pragma unroll
    for (int kc = 0; kc < 2; ++kc) {
      const short8 a = *(const short8*)(Prow + k0 + kc * 32 + hi * 8);
#pragma unroll
      for (int nt = 0; nt < 4; ++nt) {
        const short8 bv =
            *(const short8*)(pvt + (nt * 16 + l15) * PVT_S + kc * 32 + hi * 8);
        acc[nt] = mfma16(a, bv, acc[nt]);
      }
    }
  }

  const int bh0 = w * 16 + hi * 4;
#pragma unroll
  for (int j = 0; j < 4; ++j) {
    const int bh = bh0 + j;
    float* o = PP + (((size_t)ks * 256 + qlocal) * 64 + bh) * 64;
#pragma unroll
    for (int nt = 0; nt < 4; ++nt) o[nt * 16 + l15] = acc[nt][j];
  }
}

// ---------------------------------------------------------------------------
// Normalize: ctxB = (ctxU + sum_ks PP) / l. grid 1024, block 256.
// ---------------------------------------------------------------------------
__global__ __launch_bounds__(256) void norm_kernel(
    const float* __restrict__ PP,
    const float* __restrict__ ctxU,
    const float* __restrict__ l_ws,
    bf16* __restrict__ ctxB,
    int slab) {
  const int i4 = blockIdx.x * 256 + threadIdx.x;  // 0..262143
  const int e0 = i4 * 4;
  const int dm = e0 & 1023;
  const int qlocal = (e0 >> 10) & 255;
  const int b = e0 >> 18;
  const int h = dm >> 6, d0 = dm & 63;
  const int bh = b * 16 + h;
  const int q = slab * 256 + qlocal;

  f32x4 v = *(const f32x4*)(ctxU + ((size_t)b * TT + q) * DM + dm);
#pragma unroll
  for (int ks = 0; ks < 4; ++ks)
    v += *(const f32x4*)(PP + (((size_t)ks * 256 + qlocal) * 64 + bh) * 64 + d0);
  const float invl = 1.0f / l_ws[(size_t)bh * TT + q];
  bf16 o[4];
#pragma unroll
  for (int j = 0; j < 4; ++j) o[j] = __float2bfloat16(v[j] * invl);
  *(short4v*)(ctxB + ((size_t)b * TT + q) * DM + dm) = *(const short4v*)o;
}

// ---------------------------------------------------------------------------
// Output projection: 128x128 LDS-tiled MFMA GEMM, BK=64, 4 waves (2x2).
// grid (8 nblk, 32 mblk), block 256.
// ---------------------------------------------------------------------------
__global__ __launch_bounds__(256) void outproj_mfma_kernel(
    const bf16* __restrict__ A,   // [4096][1024] bf16
    const bf16* __restrict__ Bt,  // [1024 n][1024 k] bf16
    float* __restrict__ C) {
  __shared__ __align__(16) bf16 As[128 * 72];
  __shared__ __align__(16) bf16 Bs[128 * 72];
  const int n0 = blockIdx.x * 128;
  const int m0 = blockIdx.y * 128;
  const int tid = threadIdx.x;
  const int w = tid >> 6, lane = tid & 63, l15 = lane & 15, hi = lane >> 4;
  const int wm = w >> 1, wn = w & 1;

  f32x4 acc[4][4];
#pragma unroll
  for (int i = 0; i < 4; ++i)
#pragma unroll
    for (int j = 0; j < 4; ++j) acc[i][j] = (f32x4){0.f, 0.f, 0.f, 0.f};

  const int sr = tid >> 1, sc = (tid & 1) * 32;
  for (int k0 = 0; k0 < 1024; k0 += 64) {
    __syncthreads();
    {
      const bf16* as = A + (size_t)(m0 + sr) * 1024 + k0 + sc;
      const bf16* bs = Bt + (size_t)(n0 + sr) * 1024 + k0 + sc;
#pragma unroll
      for (int ii = 0; ii < 32; ii += 8) {
        *(short8*)(As + sr * 72 + sc + ii) = *(const short8*)(as + ii);
        *(short8*)(Bs + sr * 72 + sc + ii) = *(const short8*)(bs + ii);
      }
    }
    __syncthreads();
#pragma unroll
    for (int kc = 0; kc < 2; ++kc) {
      short8 a[4], b[4];
#pragma unroll
      for (int i = 0; i < 4; ++i)
        a[i] = *(const short8*)(As + (wm * 64 + i * 16 + l15) * 72 + kc * 32 +
                                hi * 8);
#pragma unroll
      for (int j = 0; j < 4; ++j)
        b[j] = *(const short8*)(Bs + (wn * 64 + j * 16 + l15) * 72 + kc * 32 +
                                hi * 8);
#pragma unroll
      for (int i = 0; i < 4; ++i)
#pragma unroll
        for (int j = 0; j < 4; ++j) acc[i][j] = mfma16(a[i], b[j], acc[i][j]);
    }
  }
#pragma unroll
  for (int i = 0; i < 4; ++i) {
#pragma unroll
    for (int jj = 0; jj < 4; ++jj) {
      const size_t row = (size_t)(m0 + wm * 64 + i * 16 + hi * 4 + jj) * 1024;
#pragma unroll
      for (int j = 0; j < 4; ++j)
        C[row + n0 + wn * 64 + j * 16 + l15] = acc[i][j][jj];
    }
  }
}

// ---------------------------------------------------------------------------
extern "C" void kernel_launch(void* const* d_in, const int* in_sizes, int n_in,
                              void* d_out, int out_size, void* d_ws,
                              size_t ws_size, hipStream_t stream) {
  const float* x = (const float*)d_in[0];
  const float* WQ = (const float*)d_in[1];
  const float* WK = (const float*)d_in[2];
  const float* WV = (const float*)d_in[3];
  const float* WZ = (const float*)d_in[4];
  const float* posK = (const float*)d_in[5];
  const float* posV = (const float*)d_in[6];
  const float* maskp = (const float*)d_in[7];
  const int* pos = (const int*)d_in[8];
  float* out = (float*)d_out;

  char* p = (char*)d_ws;
  bf16* Qb = (bf16*)p;        p += (size_t)64 * 1024 * 64 * 2;   // 8 MB
  bf16* Kb = (bf16*)p;        p += (size_t)64 * 1024 * 64 * 2;   // 8 MB
  bf16* Vb = (bf16*)p;        p += (size_t)64 * 1024 * 64 * 2;   // 8 MB
  bf16* Vt = (bf16*)p;        p += (size_t)64 * 64 * 1024 * 2;   // 8 MB
  bf16* posKbf = (bf16*)p;    p += (size_t)2048 * 64 * 2;        // 256 KB
  bf16* WzT = (bf16*)p;       p += (size_t)1024 * 1024 * 2;      // 2 MB
  bf16* Pws = (bf16*)p;       p += (size_t)256 * 64 * 1024 * 2;  // 32 MB
  float* l_ws = (float*)p;    p += (size_t)64 * 1024 * 4;        // 256 KB
  float* ctxU = (float*)p;    p += (size_t)4 * 1024 * 1024 * 4;  // 16 MB
  bf16* ctxB = (bf16*)p;      p += (size_t)4 * 1024 * 1024 * 2;  // 8 MB
  float* PP = (float*)p;      p += (size_t)4 * 256 * 64 * 64 * 4; // 16 MB

  // Aliases (dead-range reuse, safe under stream ordering):
  bf16* xb = (bf16*)ctxU;  // xb dead after qkv; ctxU written later
  bf16* Wt = ctxB;         // Wt dead after qkv; ctxB written later

  xb_kernel<<<2048, 256, 0, stream>>>(x, xb);
  prep_w_kernel<<<dim3(16, 3), 256, 0, stream>>>(WQ, WK, WV, Wt);
  prep_posk_kernel<<<512, 256, 0, stream>>>(posK, posKbf);
  trans_wz_kernel<<<dim3(16, 16), 256, 0, stream>>>(WZ, WzT);
  qkv_mfma_kernel<<<dim3(16, 64), 256, 0, stream>>>(xb, Wt, Qb, Kb, Vb);
  trans_v_kernel<<<dim3(16, 64), 256, 0, stream>>>(Vb, Vt);

  for (int slab = 0; slab < 4; ++slab) {
    score_pv_kernel<<<dim3(64, 16), 256, 0, stream>>>(
        Qb, Kb, posKbf, Vt, maskp, pos, Pws, l_ws, ctxU, slab);
    pv_part_kernel<<<dim3(256, 4), 256, 0, stream>>>(Pws, posV, pos, PP, slab);
    norm_kernel<<<1024, 256, 0, stream>>>(PP, ctxU, l_ws, ctxB, slab);
  }
  outproj_mfma_kernel<<<dim3(8, 32), 256, 0, stream>>>(ctxB, WzT, out);
}

// Round 10
// 410.565 us; speedup vs baseline: 1.0888x; 1.0888x over previous
//
#include <hip/hip_runtime.h>
#include <hip/hip_bf16.h>

#define BB 4
#define TT 1024
#define DM 1024
#define HH 16

typedef __attribute__((ext_vector_type(8))) short short8;
typedef __attribute__((ext_vector_type(4))) short short4v;
typedef __attribute__((ext_vector_type(4))) float f32x4;
typedef __hip_bfloat16 bf16;

__device__ __forceinline__ f32x4 mfma16(short8 a, short8 b, f32x4 c) {
  return __builtin_amdgcn_mfma_f32_16x16x32_bf16(a, b, c, 0, 0, 0);
}

// ---------------------------------------------------------------------------
// x fp32 -> bf16, 8 elems/thread. grid 2048.
// ---------------------------------------------------------------------------
__global__ __launch_bounds__(256) void xb_kernel(
    const float* __restrict__ x, bf16* __restrict__ xb) {
  const size_t i = ((size_t)blockIdx.x * 256 + threadIdx.x) * 8;
  bf16 tmp[8];
#pragma unroll
  for (int j = 0; j < 8; ++j) tmp[j] = __float2bfloat16(x[i + j]);
  *(short8*)(xb + i) = *(const short8*)tmp;
}

// ---------------------------------------------------------------------------
// pack pos (u16, low) + mask (top 16 bits of fp32, high) into one u32.
// grid 4096 x 256 = 1M elements.
// ---------------------------------------------------------------------------
__global__ __launch_bounds__(256) void pack_pm_kernel(
    const int* __restrict__ pos, const float* __restrict__ maskp,
    unsigned* __restrict__ pm) {
  const size_t i = (size_t)blockIdx.x * 256 + threadIdx.x;
  const unsigned mb = __float_as_uint(maskp[i]) & 0xffff0000u;
  pm[i] = mb | (unsigned)pos[i];
}

// ---------------------------------------------------------------------------
// W_{Q,K,V} fp32 [16][64 d][64 e] -> Wt bf16 [3][16][64 e][64 d] (transposed)
// grid (16 h, 3 m)
// ---------------------------------------------------------------------------
__global__ __launch_bounds__(256) void prep_w_kernel(
    const float* __restrict__ WQ, const float* __restrict__ WK,
    const float* __restrict__ WV, bf16* __restrict__ Wt) {
  __shared__ bf16 tl[64][72];
  const int h = blockIdx.x, m = blockIdx.y;
  const float* W = (m == 0 ? WQ : (m == 1 ? WK : WV)) + h * 4096;
  const int tid = threadIdx.x;
  const int r = tid >> 2, c = (tid & 3) * 16;
#pragma unroll
  for (int i = 0; i < 16; ++i)
    tl[r][c + i] = __float2bfloat16(W[r * 64 + c + i]);  // tl[d][e]
  __syncthreads();
  bf16* o = Wt + ((size_t)(m * 16 + h) * 64 + r) * 64 + c;  // [e=r][d=c..]
#pragma unroll
  for (int i = 0; i < 16; ++i) o[i] = tl[c + i][r];
}

// ---------------------------------------------------------------------------
// prep: posK fp32 [2047][64] -> bf16 [2048][64] (row 2047 zeroed)
// ---------------------------------------------------------------------------
__global__ __launch_bounds__(256) void prep_posk_kernel(
    const float* __restrict__ posK, bf16* __restrict__ posKbf) {
  const int idx = blockIdx.x * 256 + threadIdx.x;
  const int p = idx >> 6, d = idx & 63;
  const float v = (p < 2047) ? posK[(size_t)p * 64 + d] : 0.f;
  posKbf[idx] = __float2bfloat16(v);
}

// ---------------------------------------------------------------------------
// prep: WzT bf16 [n][k] = Wz fp32 [k][n]
// ---------------------------------------------------------------------------
__global__ __launch_bounds__(256) void trans_wz_kernel(
    const float* __restrict__ Wz, bf16* __restrict__ WzT) {
  __shared__ bf16 tile[64][72];
  const int k0 = blockIdx.y * 64, n0 = blockIdx.x * 64;
  const int tid = threadIdx.x;
  const int r = tid >> 2, c = (tid & 3) * 16;
  const float* s = Wz + (size_t)(k0 + r) * 1024 + n0 + c;
#pragma unroll
  for (int i = 0; i < 16; ++i) tile[r][c + i] = __float2bfloat16(s[i]);
  __syncthreads();
  const int n = tid >> 2;
  bf16* o = WzT + (size_t)(n0 + n) * 1024 + k0 + c;
#pragma unroll
  for (int i = 0; i < 16; ++i) o[i] = tile[c + i][n];
}

// ---------------------------------------------------------------------------
// transpose V: [bh][1024][64] bf16 -> Vt [bh][64][1024] bf16
// ---------------------------------------------------------------------------
__global__ __launch_bounds__(256) void trans_v_kernel(
    const bf16* __restrict__ src, bf16* __restrict__ dst) {
  __shared__ bf16 tile[64][72];
  const int bh = blockIdx.y, t0 = blockIdx.x * 64;
  const int tid = threadIdx.x;
  const int r = tid >> 2, c = (tid & 3) * 16;
  const bf16* s = src + ((size_t)bh * TT + t0 + r) * 64 + c;
  *(short8*)(&tile[r][c]) = *(const short8*)(s);
  *(short8*)(&tile[r][c + 8]) = *(const short8*)(s + 8);
  __syncthreads();
  const int d = tid >> 2;
  bf16* o = dst + ((size_t)bh * 64 + d) * TT + t0 + c;
#pragma unroll
  for (int i = 0; i < 16; ++i) o[i] = tile[c + i][d];
}

// ---------------------------------------------------------------------------
// QKV projection via MFMA. grid (16 ttiles, 64 bh), block 256 (4 waves).
// ---------------------------------------------------------------------------
__global__ __launch_bounds__(256) void qkv_mfma_kernel(
    const bf16* __restrict__ xb, const bf16* __restrict__ Wt,
    bf16* __restrict__ Qg, bf16* __restrict__ Kg, bf16* __restrict__ Vg) {
  __shared__ __align__(16) bf16 xs[64 * 72];
  const int bh = blockIdx.y;
  const int b = bh >> 4, h = bh & 15;
  const int t0 = blockIdx.x * 64;
  const int tid = threadIdx.x;
  const int w = tid >> 6, lane = tid & 63, l15 = lane & 15, hi = lane >> 4;

  {
    const int r = tid >> 2, c = (tid & 3) * 16;
    const bf16* src = xb + ((size_t)b * TT + t0 + r) * DM + h * 64 + c;
    *(short8*)(xs + r * 72 + c) = *(const short8*)(src);
    *(short8*)(xs + r * 72 + c + 8) = *(const short8*)(src + 8);
  }
  __syncthreads();

  f32x4 aQ[4] = {{0.f, 0.f, 0.f, 0.f}, {0.f, 0.f, 0.f, 0.f},
                 {0.f, 0.f, 0.f, 0.f}, {0.f, 0.f, 0.f, 0.f}};
  f32x4 aK[4] = {{0.f, 0.f, 0.f, 0.f}, {0.f, 0.f, 0.f, 0.f},
                 {0.f, 0.f, 0.f, 0.f}, {0.f, 0.f, 0.f, 0.f}};
  f32x4 aV[4] = {{0.f, 0.f, 0.f, 0.f}, {0.f, 0.f, 0.f, 0.f},
                 {0.f, 0.f, 0.f, 0.f}, {0.f, 0.f, 0.f, 0.f}};
  const bf16* WtQ = Wt + (size_t)h * 4096;
  const bf16* WtK = Wt + (size_t)(16 + h) * 4096;
  const bf16* WtV = Wt + (size_t)(32 + h) * 4096;
#pragma unroll
  for (int kc = 0; kc < 2; ++kc) {
    const short8 a =
        *(const short8*)(xs + (w * 16 + l15) * 72 + kc * 32 + hi * 8);
#pragma unroll
    for (int nt = 0; nt < 4; ++nt) {
      const size_t wo = (size_t)(nt * 16 + l15) * 64 + kc * 32 + hi * 8;
      aQ[nt] = mfma16(a, *(const short8*)(WtQ + wo), aQ[nt]);
      aK[nt] = mfma16(a, *(const short8*)(WtK + wo), aK[nt]);
      aV[nt] = mfma16(a, *(const short8*)(WtV + wo), aV[nt]);
    }
  }
  const int t = t0 + w * 16 + hi * 4;
#pragma unroll
  for (int nt = 0; nt < 4; ++nt) {
#pragma unroll
    for (int j = 0; j < 4; ++j) {
      const size_t o = ((size_t)bh * TT + t + j) * 64 + nt * 16 + l15;
      Qg[o] = __float2bfloat16(aQ[nt][j]);
      Kg[o] = __float2bfloat16(aK[nt][j]);
      Vg[o] = __float2bfloat16(aV[nt][j]);
    }
  }
}

// ---------------------------------------------------------------------------
// Fused score kernel v6 = v4 structure + packed pos/mask (one u32 gather).
//  - grid (64 bh, 16 qt): same-bh blocks land on one XCD (K/Vt L2-resident).
//  - per-XCD working set: K+Vt 2MB + packed slab 1MB + posKbf 0.25MB < 4MB L2.
//  - QP phase 2-stage register pipeline; k-loop 2-stage register pipeline.
// grid (64 bh, 16 qtiles), block 256 (4 waves).
// ---------------------------------------------------------------------------
#define QP8_S 2052
#define PSM_S 72

__global__ __launch_bounds__(256, 4) void score_pv_kernel(
    const bf16* __restrict__ Qb,
    const bf16* __restrict__ Kb,
    const bf16* __restrict__ posKbf,
    const bf16* __restrict__ Vt,
    const unsigned* __restrict__ pm,   // packed mask|pos
    bf16* __restrict__ Pws,        // [256 qlocal][64 bh][1024 k]
    float* __restrict__ l_ws,      // [64 bh][1024 q]
    float* __restrict__ ctxU,      // [b][t][1024] fp32 unnormalized
    int slab) {
  __shared__ __align__(16) unsigned char QPsh[16 * QP8_S];  // 32832 B
  __shared__ __align__(16) bf16 Psm[2][16 * PSM_S];         // 4608 B
  __shared__ float lred[4][16];                             // 256 B

  const int bh = blockIdx.x;
  const int qt = blockIdx.y;
  const int qlocal0 = qt * 16;
  const int qg0 = slab * 256 + qlocal0;
  const int tid = threadIdx.x;
  const int w = tid >> 6;
  const int lane = tid & 63;
  const int l15 = lane & 15;
  const int hi = lane >> 4;

  const bf16* Qrow = Qb + ((size_t)bh * TT + qg0 + l15) * 64 + hi * 8;
  const short8 aq0 = *(const short8*)(Qrow);
  const short8 aq1 = *(const short8*)(Qrow + 32);

  // ---- QP phase: wave w covers p-tiles w*32 .. w*32+31; 2-stage pipeline
  {
    const bf16* Kp0 = posKbf + ((size_t)(w * 32 * 16 + l15)) * 64 + hi * 8;
    short8 qb0 = *(const short8*)(Kp0);
    short8 qb1 = *(const short8*)(Kp0 + 32);
    for (int i = 0; i < 32; ++i) {
      const int pt = w * 32 + i;
      const short8 cb0 = qb0, cb1 = qb1;
      {
        const int ptn = w * 32 + ((i + 1) & 31);
        const bf16* Kpn = posKbf + ((size_t)(ptn * 16 + l15)) * 64 + hi * 8;
        qb0 = *(const short8*)(Kpn);
        qb1 = *(const short8*)(Kpn + 32);
      }
      f32x4 acc = {0.f, 0.f, 0.f, 0.f};
      acc = mfma16(aq0, cb0, acc);
      acc = mfma16(aq1, cb1, acc);
      const int p01 = __builtin_amdgcn_cvt_pk_fp8_f32(acc[0], acc[1], 0, false);
      const int p23 = __builtin_amdgcn_cvt_pk_fp8_f32(acc[2], acc[3], 0, false);
      const int off = pt * 16 + l15;
      QPsh[(hi * 4 + 0) * QP8_S + off] = (unsigned char)(p01 & 0xff);
      QPsh[(hi * 4 + 1) * QP8_S + off] = (unsigned char)((p01 >> 8) & 0xff);
      QPsh[(hi * 4 + 2) * QP8_S + off] = (unsigned char)(p23 & 0xff);
      QPsh[(hi * 4 + 3) * QP8_S + off] = (unsigned char)((p23 >> 8) & 0xff);
    }
  }
  __syncthreads();

  // wave w owns PV output d-tile [w*16, w*16+16)
  f32x4 acc_pv = {0.f, 0.f, 0.f, 0.f};
  float lp[4] = {0.f, 0.f, 0.f, 0.f};
  const int kk = w * 16 + l15;
  const bf16* Kbh = Kb + (size_t)bh * TT * 64;
  const bf16* Vtrow = Vt + ((size_t)bh * 64 + w * 16 + l15) * TT;

  // prologue: stage tile 0 operands in registers
  short8 nb0 = *(const short8*)(Kbh + (size_t)kk * 64 + hi * 8);
  short8 nb1 = *(const short8*)(Kbh + (size_t)kk * 64 + 32 + hi * 8);
  short8 nv0 = *(const short8*)(Vtrow + hi * 8);
  short8 nv1 = *(const short8*)(Vtrow + 32 + hi * 8);
  unsigned npm[4];
#pragma unroll
  for (int j = 0; j < 4; ++j)
    npm[j] = pm[(size_t)(qg0 + hi * 4 + j) * TT + kk];

  for (int it = 0; it < 16; ++it) {
    const int k0 = it * 64;
    bf16* PsmC = &Psm[it & 1][0];
    const short8 cb0 = nb0, cb1 = nb1, cv0 = nv0, cv1 = nv1;
    unsigned cpm[4];
#pragma unroll
    for (int j = 0; j < 4; ++j) cpm[j] = npm[j];
    {
      const int k0n = ((it + 1) & 15) * 64;
      nb0 = *(const short8*)(Kbh + (size_t)(k0n + kk) * 64 + hi * 8);
      nb1 = *(const short8*)(Kbh + (size_t)(k0n + kk) * 64 + 32 + hi * 8);
      nv0 = *(const short8*)(Vtrow + k0n + hi * 8);
      nv1 = *(const short8*)(Vtrow + k0n + 32 + hi * 8);
#pragma unroll
      for (int j = 0; j < 4; ++j)
        npm[j] = pm[(size_t)(qg0 + hi * 4 + j) * TT + k0n + kk];
    }
    // content scores from registers
    f32x4 s = {0.f, 0.f, 0.f, 0.f};
    s = mfma16(aq0, cb0, s);
    s = mfma16(aq1, cb1, s);
    // + QP[pos] (fp8 LDS gather) + mask, *0.125, exp -> Psm[cur]
#pragma unroll
    for (int j = 0; j < 4; ++j) {
      const int q = hi * 4 + j;
      const unsigned pmv = cpm[j];
      const float qp = __builtin_amdgcn_cvt_f32_fp8(
          (int)QPsh[q * QP8_S + (pmv & 0xffffu)], 0);
      float sv = s[j] + qp;
      sv = (sv + __uint_as_float(pmv & 0xffff0000u)) * 0.125f;
      const float pe = __expf(sv);
      lp[j] += pe;
      PsmC[q * PSM_S + kk] = __float2bfloat16(pe);
    }
    __syncthreads();
    // store P tile to global (unnormalized), coalesced via LDS
    {
      const int r = tid >> 4, c = (tid & 15) * 4;
      *(short4v*)(Pws + ((size_t)(qlocal0 + r) * 64 + bh) * TT + k0 + c) =
          *(const short4v*)(PsmC + r * PSM_S + c);
    }
    // PV MFMAs from registers (Vt) + LDS (P)
    {
      const short8 pa0 = *(const short8*)(PsmC + l15 * PSM_S + hi * 8);
      acc_pv = mfma16(pa0, cv0, acc_pv);
      const short8 pa1 = *(const short8*)(PsmC + l15 * PSM_S + 32 + hi * 8);
      acc_pv = mfma16(pa1, cv1, acc_pv);
    }
  }

  // l row-sums
#pragma unroll
  for (int j = 0; j < 4; ++j) {
    float v = lp[j];
    v += __shfl_xor(v, 1);
    v += __shfl_xor(v, 2);
    v += __shfl_xor(v, 4);
    v += __shfl_xor(v, 8);
    if (l15 == 0) lred[w][hi * 4 + j] = v;
  }
  __syncthreads();
  if (tid < 16) {
    const float l = lred[0][tid] + lred[1][tid] + lred[2][tid] + lred[3][tid];
    l_ws[(size_t)bh * TT + qg0 + tid] = l;
  }
  {
    const int b = bh >> 4, h = bh & 15;
#pragma unroll
    for (int j = 0; j < 4; ++j) {
      const int q = hi * 4 + j;
      ctxU[((size_t)b * TT + qg0 + q) * DM + h * 64 + w * 16 + l15] = acc_pv[j];
    }
  }
}

// ---------------------------------------------------------------------------
// PV partial kernel (k-split x4): grid (256 q, 4 ks), block 256.
// ---------------------------------------------------------------------------
#define PVT_S 72
__global__ __launch_bounds__(256) void pv_part_kernel(
    const bf16* __restrict__ Pws,
    const float* __restrict__ posV,
    const unsigned* __restrict__ pm,
    float* __restrict__ PP,   // [4][256][64][64] fp32
    int slab) {
  __shared__ __align__(16) bf16 PVt[2][64 * PVT_S];
  __shared__ unsigned short possh[256];

  const int qlocal = blockIdx.x;
  const int q = slab * 256 + qlocal;
  const int ks = blockIdx.y;
  const int kbase = ks * 256;
  const int tid = threadIdx.x;
  const int w = tid >> 6, lane = tid & 63, l15 = lane & 15, hi = lane >> 4;

  possh[tid] = (unsigned short)(pm[(size_t)q * TT + kbase + tid] & 0xffffu);
  __syncthreads();

  f32x4 acc[4] = {{0.f, 0.f, 0.f, 0.f}, {0.f, 0.f, 0.f, 0.f},
                  {0.f, 0.f, 0.f, 0.f}, {0.f, 0.f, 0.f, 0.f}};
  const bf16* Prow = Pws + ((size_t)qlocal * 64 + w * 16 + l15) * TT;

  for (int it = 0; it < 4; ++it) {
    const int k0 = kbase + it * 64;
    bf16* pvt = &PVt[it & 1][0];
    {
      const int kr = lane;
      const int dc = w * 16;
      const int p = possh[it * 64 + kr];
      const float* src = posV + (size_t)p * 64 + dc;
#pragma unroll
      for (int ii = 0; ii < 16; ii += 4) {
        const f32x4 v = *(const f32x4*)(src + ii);
        pvt[(dc + ii + 0) * PVT_S + kr] = __float2bfloat16(v[0]);
        pvt[(dc + ii + 1) * PVT_S + kr] = __float2bfloat16(v[1]);
        pvt[(dc + ii + 2) * PVT_S + kr] = __float2bfloat16(v[2]);
        pvt[(dc + ii + 3) * PVT_S + kr] = __float2bfloat16(v[3]);
      }
    }
    __syncthreads();
#pragma unroll
    for (int kc = 0; kc < 2; ++kc) {
      const short8 a = *(const short8*)(Prow + k0 + kc * 32 + hi * 8);
#pragma unroll
      for (int nt = 0; nt < 4; ++nt) {
        const short8 bv =
            *(const short8*)(pvt + (nt * 16 + l15) * PVT_S + kc * 32 + hi * 8);
        acc[nt] = mfma16(a, bv, acc[nt]);
      }
    }
  }

  const int bh0 = w * 16 + hi * 4;
#pragma unroll
  for (int j = 0; j < 4; ++j) {
    const int bh = bh0 + j;
    float* o = PP + (((size_t)ks * 256 + qlocal) * 64 + bh) * 64;
#pragma unroll
    for (int nt = 0; nt < 4; ++nt) o[nt * 16 + l15] = acc[nt][j];
  }
}

// ---------------------------------------------------------------------------
// Normalize: ctxB = (ctxU + sum_ks PP) / l. grid 1024, block 256.
// ---------------------------------------------------------------------------
__global__ __launch_bounds__(256) void norm_kernel(
    const float* __restrict__ PP,
    const float* __restrict__ ctxU,
    const float* __restrict__ l_ws,
    bf16* __restrict__ ctxB,
    int slab) {
  const int i4 = blockIdx.x * 256 + threadIdx.x;  // 0..262143
  const int e0 = i4 * 4;
  const int dm = e0 & 1023;
  const int qlocal = (e0 >> 10) & 255;
  const int b = e0 >> 18;
  const int h = dm >> 6, d0 = dm & 63;
  const int bh = b * 16 + h;
  const int q = slab * 256 + qlocal;

  f32x4 v = *(const f32x4*)(ctxU + ((size_t)b * TT + q) * DM + dm);
#pragma unroll
  for (int ks = 0; ks < 4; ++ks)
    v += *(const f32x4*)(PP + (((size_t)ks * 256 + qlocal) * 64 + bh) * 64 + d0);
  const float invl = 1.0f / l_ws[(size_t)bh * TT + q];
  bf16 o[4];
#pragma unroll
  for (int j = 0; j < 4; ++j) o[j] = __float2bfloat16(v[j] * invl);
  *(short4v*)(ctxB + ((size_t)b * TT + q) * DM + dm) = *(const short4v*)o;
}

// ---------------------------------------------------------------------------
// Output projection: 128x128 LDS-tiled MFMA GEMM, BK=64, 4 waves (2x2).
// grid (8 nblk, 32 mblk), block 256.
// ---------------------------------------------------------------------------
__global__ __launch_bounds__(256) void outproj_mfma_kernel(
    const bf16* __restrict__ A,   // [4096][1024] bf16
    const bf16* __restrict__ Bt,  // [1024 n][1024 k] bf16
    float* __restrict__ C) {
  __shared__ __align__(16) bf16 As[128 * 72];
  __shared__ __align__(16) bf16 Bs[128 * 72];
  const int n0 = blockIdx.x * 128;
  const int m0 = blockIdx.y * 128;
  const int tid = threadIdx.x;
  const int w = tid >> 6, lane = tid & 63, l15 = lane & 15, hi = lane >> 4;
  const int wm = w >> 1, wn = w & 1;

  f32x4 acc[4][4];
#pragma unroll
  for (int i = 0; i < 4; ++i)
#pragma unroll
    for (int j = 0; j < 4; ++j) acc[i][j] = (f32x4){0.f, 0.f, 0.f, 0.f};

  const int sr = tid >> 1, sc = (tid & 1) * 32;
  for (int k0 = 0; k0 < 1024; k0 += 64) {
    __syncthreads();
    {
      const bf16* as = A + (size_t)(m0 + sr) * 1024 + k0 + sc;
      const bf16* bs = Bt + (size_t)(n0 + sr) * 1024 + k0 + sc;
#pragma unroll
      for (int ii = 0; ii < 32; ii += 8) {
        *(short8*)(As + sr * 72 + sc + ii) = *(const short8*)(as + ii);
        *(short8*)(Bs + sr * 72 + sc + ii) = *(const short8*)(bs + ii);
      }
    }
    __syncthreads();
#pragma unroll
    for (int kc = 0; kc < 2; ++kc) {
      short8 a[4], b[4];
#pragma unroll
      for (int i = 0; i < 4; ++i)
        a[i] = *(const short8*)(As + (wm * 64 + i * 16 + l15) * 72 + kc * 32 +
                                hi * 8);
#pragma unroll
      for (int j = 0; j < 4; ++j)
        b[j] = *(const short8*)(Bs + (wn * 64 + j * 16 + l15) * 72 + kc * 32 +
                                hi * 8);
#pragma unroll
      for (int i = 0; i < 4; ++i)
#pragma unroll
        for (int j = 0; j < 4; ++j) acc[i][j] = mfma16(a[i], b[j], acc[i][j]);
    }
  }
#pragma unroll
  for (int i = 0; i < 4; ++i) {
#pragma unroll
    for (int jj = 0; jj < 4; ++jj) {
      const size_t row = (size_t)(m0 + wm * 64 + i * 16 + hi * 4 + jj) * 1024;
#pragma unroll
      for (int j = 0; j < 4; ++j)
        C[row + n0 + wn * 64 + j * 16 + l15] = acc[i][j][jj];
    }
  }
}

// ---------------------------------------------------------------------------
extern "C" void kernel_launch(void* const* d_in, const int* in_sizes, int n_in,
                              void* d_out, int out_size, void* d_ws,
                              size_t ws_size, hipStream_t stream) {
  const float* x = (const float*)d_in[0];
  const float* WQ = (const float*)d_in[1];
  const float* WK = (const float*)d_in[2];
  const float* WV = (const float*)d_in[3];
  const float* WZ = (const float*)d_in[4];
  const float* posK = (const float*)d_in[5];
  const float* posV = (const float*)d_in[6];
  const float* maskp = (const float*)d_in[7];
  const int* pos = (const int*)d_in[8];
  float* out = (float*)d_out;

  char* p = (char*)d_ws;
  bf16* Qb = (bf16*)p;        p += (size_t)64 * 1024 * 64 * 2;   // 8 MB
  bf16* Kb = (bf16*)p;        p += (size_t)64 * 1024 * 64 * 2;   // 8 MB
  bf16* Vb = (bf16*)p;        p += (size_t)64 * 1024 * 64 * 2;   // 8 MB
  bf16* Vt = (bf16*)p;        p += (size_t)64 * 64 * 1024 * 2;   // 8 MB
  bf16* posKbf = (bf16*)p;    p += (size_t)2048 * 64 * 2;        // 256 KB
  bf16* WzT = (bf16*)p;       p += (size_t)1024 * 1024 * 2;      // 2 MB
  bf16* Pws = (bf16*)p;       p += (size_t)256 * 64 * 1024 * 2;  // 32 MB
  float* l_ws = (float*)p;    p += (size_t)64 * 1024 * 4;        // 256 KB
  float* ctxU = (float*)p;    p += (size_t)4 * 1024 * 1024 * 4;  // 16 MB
  bf16* ctxB = (bf16*)p;      p += (size_t)4 * 1024 * 1024 * 2;  // 8 MB
  float* PP = (float*)p;      p += (size_t)4 * 256 * 64 * 64 * 4; // 16 MB
  unsigned* pm_ws = (unsigned*)p; p += (size_t)1024 * 1024 * 4;   // 4 MB

  // Aliases (dead-range reuse, safe under stream ordering):
  bf16* xb = (bf16*)ctxU;  // xb dead after qkv; ctxU written later
  bf16* Wt = ctxB;         // Wt dead after qkv; ctxB written later

  xb_kernel<<<2048, 256, 0, stream>>>(x, xb);
  pack_pm_kernel<<<4096, 256, 0, stream>>>(pos, maskp, pm_ws);
  prep_w_kernel<<<dim3(16, 3), 256, 0, stream>>>(WQ, WK, WV, Wt);
  prep_posk_kernel<<<512, 256, 0, stream>>>(posK, posKbf);
  trans_wz_kernel<<<dim3(16, 16), 256, 0, stream>>>(WZ, WzT);
  qkv_mfma_kernel<<<dim3(16, 64), 256, 0, stream>>>(xb, Wt, Qb, Kb, Vb);
  trans_v_kernel<<<dim3(16, 64), 256, 0, stream>>>(Vb, Vt);

  for (int slab = 0; slab < 4; ++slab) {
    score_pv_kernel<<<dim3(64, 16), 256, 0, stream>>>(
        Qb, Kb, posKbf, Vt, pm_ws, Pws, l_ws, ctxU, slab);
    pv_part_kernel<<<dim3(256, 4), 256, 0, stream>>>(Pws, posV, pm_ws, PP,
                                                     slab);
    norm_kernel<<<1024, 256, 0, stream>>>(PP, ctxU, l_ws, ctxB, slab);
  }
  outproj_mfma_kernel<<<dim3(8, 32), 256, 0, stream>>>(ctxB, WzT, out);
}

// Round 11
// 409.933 us; speedup vs baseline: 1.0905x; 1.0015x over previous
//
#include <hip/hip_runtime.h>
#include <hip/hip_bf16.h>

#define BB 4
#define TT 1024
#define DM 1024
#define HH 16

typedef __attribute__((ext_vector_type(8))) short short8;
typedef __attribute__((ext_vector_type(4))) short short4v;
typedef __attribute__((ext_vector_type(4))) float f32x4;
typedef __hip_bfloat16 bf16;

__device__ __forceinline__ f32x4 mfma16(short8 a, short8 b, f32x4 c) {
  return __builtin_amdgcn_mfma_f32_16x16x32_bf16(a, b, c, 0, 0, 0);
}

// ---------------------------------------------------------------------------
// x fp32 -> bf16, 8 elems/thread. grid 2048.
// ---------------------------------------------------------------------------
__global__ __launch_bounds__(256) void xb_kernel(
    const float* __restrict__ x, bf16* __restrict__ xb) {
  const size_t i = ((size_t)blockIdx.x * 256 + threadIdx.x) * 8;
  bf16 tmp[8];
#pragma unroll
  for (int j = 0; j < 8; ++j) tmp[j] = __float2bfloat16(x[i + j]);
  *(short8*)(xb + i) = *(const short8*)tmp;
}

// ---------------------------------------------------------------------------
// pack pos (u16, low) + mask (top 16 bits of fp32, high) into one u32.
// ---------------------------------------------------------------------------
__global__ __launch_bounds__(256) void pack_pm_kernel(
    const int* __restrict__ pos, const float* __restrict__ maskp,
    unsigned* __restrict__ pm) {
  const size_t i = (size_t)blockIdx.x * 256 + threadIdx.x;
  const unsigned mb = __float_as_uint(maskp[i]) & 0xffff0000u;
  pm[i] = mb | (unsigned)pos[i];
}

// ---------------------------------------------------------------------------
// W_{Q,K,V} fp32 [16][64 d][64 e] -> Wt bf16 [3][16][64 e][64 d] (transposed)
// ---------------------------------------------------------------------------
__global__ __launch_bounds__(256) void prep_w_kernel(
    const float* __restrict__ WQ, const float* __restrict__ WK,
    const float* __restrict__ WV, bf16* __restrict__ Wt) {
  __shared__ bf16 tl[64][72];
  const int h = blockIdx.x, m = blockIdx.y;
  const float* W = (m == 0 ? WQ : (m == 1 ? WK : WV)) + h * 4096;
  const int tid = threadIdx.x;
  const int r = tid >> 2, c = (tid & 3) * 16;
#pragma unroll
  for (int i = 0; i < 16; ++i)
    tl[r][c + i] = __float2bfloat16(W[r * 64 + c + i]);
  __syncthreads();
  bf16* o = Wt + ((size_t)(m * 16 + h) * 64 + r) * 64 + c;
#pragma unroll
  for (int i = 0; i < 16; ++i) o[i] = tl[c + i][r];
}

// ---------------------------------------------------------------------------
// prep: posK fp32 [2047][64] -> bf16 [2048][64] (row 2047 zeroed)
// ---------------------------------------------------------------------------
__global__ __launch_bounds__(256) void prep_posk_kernel(
    const float* __restrict__ posK, bf16* __restrict__ posKbf) {
  const int idx = blockIdx.x * 256 + threadIdx.x;
  const int p = idx >> 6, d = idx & 63;
  const float v = (p < 2047) ? posK[(size_t)p * 64 + d] : 0.f;
  posKbf[idx] = __float2bfloat16(v);
}

// ---------------------------------------------------------------------------
// prep: WzT bf16 [n][k] = Wz fp32 [k][n]
// ---------------------------------------------------------------------------
__global__ __launch_bounds__(256) void trans_wz_kernel(
    const float* __restrict__ Wz, bf16* __restrict__ WzT) {
  __shared__ bf16 tile[64][72];
  const int k0 = blockIdx.y * 64, n0 = blockIdx.x * 64;
  const int tid = threadIdx.x;
  const int r = tid >> 2, c = (tid & 3) * 16;
  const float* s = Wz + (size_t)(k0 + r) * 1024 + n0 + c;
#pragma unroll
  for (int i = 0; i < 16; ++i) tile[r][c + i] = __float2bfloat16(s[i]);
  __syncthreads();
  const int n = tid >> 2;
  bf16* o = WzT + (size_t)(n0 + n) * 1024 + k0 + c;
#pragma unroll
  for (int i = 0; i < 16; ++i) o[i] = tile[c + i][n];
}

// ---------------------------------------------------------------------------
// transpose V: [bh][1024][64] bf16 -> Vt [bh][64][1024] bf16
// ---------------------------------------------------------------------------
__global__ __launch_bounds__(256) void trans_v_kernel(
    const bf16* __restrict__ src, bf16* __restrict__ dst) {
  __shared__ bf16 tile[64][72];
  const int bh = blockIdx.y, t0 = blockIdx.x * 64;
  const int tid = threadIdx.x;
  const int r = tid >> 2, c = (tid & 3) * 16;
  const bf16* s = src + ((size_t)bh * TT + t0 + r) * 64 + c;
  *(short8*)(&tile[r][c]) = *(const short8*)(s);
  *(short8*)(&tile[r][c + 8]) = *(const short8*)(s + 8);
  __syncthreads();
  const int d = tid >> 2;
  bf16* o = dst + ((size_t)bh * 64 + d) * TT + t0 + c;
#pragma unroll
  for (int i = 0; i < 16; ++i) o[i] = tile[c + i][d];
}

// ---------------------------------------------------------------------------
// QKV projection via MFMA. grid (16 ttiles, 64 bh), block 256 (4 waves).
// ---------------------------------------------------------------------------
__global__ __launch_bounds__(256) void qkv_mfma_kernel(
    const bf16* __restrict__ xb, const bf16* __restrict__ Wt,
    bf16* __restrict__ Qg, bf16* __restrict__ Kg, bf16* __restrict__ Vg) {
  __shared__ __align__(16) bf16 xs[64 * 72];
  const int bh = blockIdx.y;
  const int b = bh >> 4, h = bh & 15;
  const int t0 = blockIdx.x * 64;
  const int tid = threadIdx.x;
  const int w = tid >> 6, lane = tid & 63, l15 = lane & 15, hi = lane >> 4;

  {
    const int r = tid >> 2, c = (tid & 3) * 16;
    const bf16* src = xb + ((size_t)b * TT + t0 + r) * DM + h * 64 + c;
    *(short8*)(xs + r * 72 + c) = *(const short8*)(src);
    *(short8*)(xs + r * 72 + c + 8) = *(const short8*)(src + 8);
  }
  __syncthreads();

  f32x4 aQ[4] = {{0.f, 0.f, 0.f, 0.f}, {0.f, 0.f, 0.f, 0.f},
                 {0.f, 0.f, 0.f, 0.f}, {0.f, 0.f, 0.f, 0.f}};
  f32x4 aK[4] = {{0.f, 0.f, 0.f, 0.f}, {0.f, 0.f, 0.f, 0.f},
                 {0.f, 0.f, 0.f, 0.f}, {0.f, 0.f, 0.f, 0.f}};
  f32x4 aV[4] = {{0.f, 0.f, 0.f, 0.f}, {0.f, 0.f, 0.f, 0.f},
                 {0.f, 0.f, 0.f, 0.f}, {0.f, 0.f, 0.f, 0.f}};
  const bf16* WtQ = Wt + (size_t)h * 4096;
  const bf16* WtK = Wt + (size_t)(16 + h) * 4096;
  const bf16* WtV = Wt + (size_t)(32 + h) * 4096;
#pragma unroll
  for (int kc = 0; kc < 2; ++kc) {
    const short8 a =
        *(const short8*)(xs + (w * 16 + l15) * 72 + kc * 32 + hi * 8);
#pragma unroll
    for (int nt = 0; nt < 4; ++nt) {
      const size_t wo = (size_t)(nt * 16 + l15) * 64 + kc * 32 + hi * 8;
      aQ[nt] = mfma16(a, *(const short8*)(WtQ + wo), aQ[nt]);
      aK[nt] = mfma16(a, *(const short8*)(WtK + wo), aK[nt]);
      aV[nt] = mfma16(a, *(const short8*)(WtV + wo), aV[nt]);
    }
  }
  const int t = t0 + w * 16 + hi * 4;
#pragma unroll
  for (int nt = 0; nt < 4; ++nt) {
#pragma unroll
    for (int j = 0; j < 4; ++j) {
      const size_t o = ((size_t)bh * TT + t + j) * 64 + nt * 16 + l15;
      Qg[o] = __float2bfloat16(aQ[nt][j]);
      Kg[o] = __float2bfloat16(aK[nt][j]);
      Vg[o] = __float2bfloat16(aV[nt][j]);
    }
  }
}

// ---------------------------------------------------------------------------
// Fused score kernel v7: barrier-free k-loop with wave-local P.
//  - v6 gather shape kept: q = hi*4+j, k = w*16+l15 (4 lines/instr pm).
//  - Each wave pairs two 64-k half-tiles into a private [16q][32k] LDS
//    scratch (stride 40 shorts); transpose S->A-frag within the wave
//    (same-wave LDS RAW, lgkmcnt only, NO barrier).
//  - PV: 4 MFMAs (K=32) per pair, Vt as B-frags; Pws store wave-local.
//  - Cross-wave combine (l, ctx k-partials) in a 2-barrier epilogue.
// grid (64 bh, 16 qt), block 256 (4 waves).
// ---------------------------------------------------------------------------
#define QP8_S 2052
#define PSMW 40   // shorts per q-row in wave-private P scratch (80 B)

__global__ __launch_bounds__(256, 4) void score_pv_kernel(
    const bf16* __restrict__ Qb,
    const bf16* __restrict__ Kb,
    const bf16* __restrict__ posKbf,
    const bf16* __restrict__ Vt,
    const unsigned* __restrict__ pm,   // packed mask|pos
    bf16* __restrict__ Pws,        // [256 qlocal][64 bh][1024 k]
    float* __restrict__ l_ws,      // [64 bh][1024 q]
    float* __restrict__ ctxU,      // [b][t][1024] fp32 unnormalized
    int slab) {
  __shared__ __align__(16) unsigned char QPsh[16 * QP8_S];  // 32832 B
  __shared__ __align__(16) bf16 Psm[4 * 16 * PSMW];         // 5120 B
  __shared__ float lred[4][16];                             // 256 B
  float* red = (float*)QPsh;  // epilogue reuse: [64][65] fp32 = 16640 B

  const int bh = blockIdx.x;
  const int qt = blockIdx.y;
  const int qlocal0 = qt * 16;
  const int qg0 = slab * 256 + qlocal0;
  const int tid = threadIdx.x;
  const int w = tid >> 6;
  const int lane = tid & 63;
  const int l15 = lane & 15;
  const int hi = lane >> 4;

  const bf16* Qrow = Qb + ((size_t)bh * TT + qg0 + l15) * 64 + hi * 8;
  const short8 aq0 = *(const short8*)(Qrow);
  const short8 aq1 = *(const short8*)(Qrow + 32);

  // ---- QP phase: wave w covers p-tiles w*32 .. w*32+31; 2-stage pipeline
  {
    const bf16* Kp0 = posKbf + ((size_t)(w * 32 * 16 + l15)) * 64 + hi * 8;
    short8 qb0 = *(const short8*)(Kp0);
    short8 qb1 = *(const short8*)(Kp0 + 32);
    for (int i = 0; i < 32; ++i) {
      const int pt = w * 32 + i;
      const short8 cb0 = qb0, cb1 = qb1;
      {
        const int ptn = w * 32 + ((i + 1) & 31);
        const bf16* Kpn = posKbf + ((size_t)(ptn * 16 + l15)) * 64 + hi * 8;
        qb0 = *(const short8*)(Kpn);
        qb1 = *(const short8*)(Kpn + 32);
      }
      f32x4 acc = {0.f, 0.f, 0.f, 0.f};
      acc = mfma16(aq0, cb0, acc);
      acc = mfma16(aq1, cb1, acc);
      const int p01 = __builtin_amdgcn_cvt_pk_fp8_f32(acc[0], acc[1], 0, false);
      const int p23 = __builtin_amdgcn_cvt_pk_fp8_f32(acc[2], acc[3], 0, false);
      const int off = pt * 16 + l15;
      QPsh[(hi * 4 + 0) * QP8_S + off] = (unsigned char)(p01 & 0xff);
      QPsh[(hi * 4 + 1) * QP8_S + off] = (unsigned char)((p01 >> 8) & 0xff);
      QPsh[(hi * 4 + 2) * QP8_S + off] = (unsigned char)(p23 & 0xff);
      QPsh[(hi * 4 + 3) * QP8_S + off] = (unsigned char)((p23 >> 8) & 0xff);
    }
  }
  __syncthreads();

  // ---- barrier-free k-loop (8 pairs of 64-k half-tiles)
  f32x4 accp[4] = {{0.f, 0.f, 0.f, 0.f}, {0.f, 0.f, 0.f, 0.f},
                   {0.f, 0.f, 0.f, 0.f}, {0.f, 0.f, 0.f, 0.f}};
  float lp[4] = {0.f, 0.f, 0.f, 0.f};
  const int kk = w * 16 + l15;
  const bf16* Kbh = Kb + (size_t)bh * TT * 64;
  const bf16* Vtbh = Vt + (size_t)bh * 64 * TT;
  bf16* psm = &Psm[w * 16 * PSMW];
  // Vt B-frag column offset within the wave's 32-k (pair) window:
  const int vcoff = (hi & 1) * 8 + (hi >> 1) * 64;

  for (int pr = 0; pr < 8; ++pr) {
    const int kp = pr * 128;
    // loads for both halves (no barriers anywhere in this loop)
    const bf16* kr0 = Kbh + (size_t)(kp + kk) * 64 + hi * 8;
    const bf16* kr1 = Kbh + (size_t)(kp + 64 + kk) * 64 + hi * 8;
    const short8 kb00 = *(const short8*)(kr0);
    const short8 kb01 = *(const short8*)(kr0 + 32);
    const short8 kb10 = *(const short8*)(kr1);
    const short8 kb11 = *(const short8*)(kr1 + 32);
    short8 vb[4];
#pragma unroll
    for (int nt = 0; nt < 4; ++nt)
      vb[nt] = *(const short8*)(Vtbh + (size_t)(nt * 16 + l15) * TT + kp +
                                w * 16 + vcoff);
    unsigned cpm[8];
#pragma unroll
    for (int t = 0; t < 2; ++t)
#pragma unroll
      for (int j = 0; j < 4; ++j)
        cpm[t * 4 + j] =
            pm[(size_t)(qg0 + hi * 4 + j) * TT + kp + t * 64 + kk];

    // compute both halves: S tile -> exp -> wave-private Psm [16q][32k]
#pragma unroll
    for (int t = 0; t < 2; ++t) {
      f32x4 s = {0.f, 0.f, 0.f, 0.f};
      s = mfma16(aq0, t == 0 ? kb00 : kb10, s);
      s = mfma16(aq1, t == 0 ? kb01 : kb11, s);
#pragma unroll
      for (int j = 0; j < 4; ++j) {
        const int q = hi * 4 + j;
        const unsigned pmv = cpm[t * 4 + j];
        const float qp = __builtin_amdgcn_cvt_f32_fp8(
            (int)QPsh[q * QP8_S + (pmv & 0xffffu)], 0);
        const float sv = (s[j] + qp + __uint_as_float(pmv & 0xffff0000u)) *
                         0.125f;
        const float pe = __expf(sv);
        lp[j] += pe;
        psm[q * PSMW + t * 16 + l15] = __float2bfloat16(pe);
      }
    }
    // PV: A-frag from wave-private Psm (same-wave RAW, lgkm-ordered)
    const short8 pa = *(const short8*)(psm + l15 * PSMW + hi * 8);
#pragma unroll
    for (int nt = 0; nt < 4; ++nt) accp[nt] = mfma16(pa, vb[nt], accp[nt]);
    // Pws store (wave-local columns)
#pragma unroll
    for (int t = 0; t < 2; ++t) {
      const short4v pw = *(const short4v*)(psm + l15 * PSMW + t * 16 + hi * 4);
      *(short4v*)(Pws + ((size_t)(qlocal0 + l15) * 64 + bh) * TT + kp +
                  t * 64 + w * 16 + hi * 4) = pw;
    }
  }

  // ---- epilogue: combine wave k-partials (2 barriers total)
  // lp[j]: partial over k = w*16+l15 (+64n). Reduce over l15 lanes.
#pragma unroll
  for (int j = 0; j < 4; ++j) {
    float v = lp[j];
    v += __shfl_xor(v, 1);
    v += __shfl_xor(v, 2);
    v += __shfl_xor(v, 4);
    v += __shfl_xor(v, 8);
    lp[j] = v;
  }
  __syncthreads();  // all QPsh gathers done before red overwrite
  if (l15 == 0) {
#pragma unroll
    for (int j = 0; j < 4; ++j) lred[w][hi * 4 + j] = lp[j];
  }
  // accp[nt][j] = ctx partial [q=hi*4+j][d=nt*16+l15] over wave's k-subset
#pragma unroll
  for (int nt = 0; nt < 4; ++nt)
#pragma unroll
    for (int j = 0; j < 4; ++j)
      red[(w * 16 + hi * 4 + j) * 65 + nt * 16 + l15] = accp[nt][j];
  __syncthreads();
  if (tid < 16) {
    const float l = lred[0][tid] + lred[1][tid] + lred[2][tid] + lred[3][tid];
    l_ws[(size_t)bh * TT + qg0 + tid] = l;
  }
  {
    const int b = bh >> 4, h = bh & 15;
    for (int i = tid; i < 1024; i += 256) {
      const int q = i >> 6, d = i & 63;
      const float v = red[(q)*65 + d] + red[(16 + q) * 65 + d] +
                      red[(32 + q) * 65 + d] + red[(48 + q) * 65 + d];
      ctxU[((size_t)b * TT + qg0 + q) * DM + h * 64 + d] = v;
    }
  }
}

// ---------------------------------------------------------------------------
// PV partial kernel (k-split x4): grid (256 q, 4 ks), block 256.
// ---------------------------------------------------------------------------
#define PVT_S 72
__global__ __launch_bounds__(256) void pv_part_kernel(
    const bf16* __restrict__ Pws,
    const float* __restrict__ posV,
    const unsigned* __restrict__ pm,
    float* __restrict__ PP,   // [4][256][64][64] fp32
    int slab) {
  __shared__ __align__(16) bf16 PVt[2][64 * PVT_S];
  __shared__ unsigned short possh[256];

  const int qlocal = blockIdx.x;
  const int q = slab * 256 + qlocal;
  const int ks = blockIdx.y;
  const int kbase = ks * 256;
  const int tid = threadIdx.x;
  const int w = tid >> 6, lane = tid & 63, l15 = lane & 15, hi = lane >> 4;

  possh[tid] = (unsigned short)(pm[(size_t)q * TT + kbase + tid] & 0xffffu);
  __syncthreads();

  f32x4 acc[4] = {{0.f, 0.f, 0.f, 0.f}, {0.f, 0.f, 0.f, 0.f},
                  {0.f, 0.f, 0.f, 0.f}, {0.f, 0.f, 0.f, 0.f}};
  const bf16* Prow = Pws + ((size_t)qlocal * 64 + w * 16 + l15) * TT;

  for (int it = 0; it < 4; ++it) {
    const int k0 = kbase + it * 64;
    bf16* pvt = &PVt[it & 1][0];
    {
      const int kr = lane;
      const int dc = w * 16;
      const int p = possh[it * 64 + kr];
      const float* src = posV + (size_t)p * 64 + dc;
#pragma unroll
      for (int ii = 0; ii < 16; ii += 4) {
        const f32x4 v = *(const f32x4*)(src + ii);
        pvt[(dc + ii + 0) * PVT_S + kr] = __float2bfloat16(v[0]);
        pvt[(dc + ii + 1) * PVT_S + kr] = __float2bfloat16(v[1]);
        pvt[(dc + ii + 2) * PVT_S + kr] = __float2bfloat16(v[2]);
        pvt[(dc + ii + 3) * PVT_S + kr] = __float2bfloat16(v[3]);
      }
    }
    __syncthreads();
#pragma unroll
    for (int kc = 0; kc < 2; ++kc) {
      const short8 a = *(const short8*)(Prow + k0 + kc * 32 + hi * 8);
#pragma unroll
      for (int nt = 0; nt < 4; ++nt) {
        const short8 bv =
            *(const short8*)(pvt + (nt * 16 + l15) * PVT_S + kc * 32 + hi * 8);
        acc[nt] = mfma16(a, bv, acc[nt]);
      }
    }
  }

  const int bh0 = w * 16 + hi * 4;
#pragma unroll
  for (int j = 0; j < 4; ++j) {
    const int bh = bh0 + j;
    float* o = PP + (((size_t)ks * 256 + qlocal) * 64 + bh) * 64;
#pragma unroll
    for (int nt = 0; nt < 4; ++nt) o[nt * 16 + l15] = acc[nt][j];
  }
}

// ---------------------------------------------------------------------------
// Normalize: ctxB = (ctxU + sum_ks PP) / l. grid 1024, block 256.
// ---------------------------------------------------------------------------
__global__ __launch_bounds__(256) void norm_kernel(
    const float* __restrict__ PP,
    const float* __restrict__ ctxU,
    const float* __restrict__ l_ws,
    bf16* __restrict__ ctxB,
    int slab) {
  const int i4 = blockIdx.x * 256 + threadIdx.x;  // 0..262143
  const int e0 = i4 * 4;
  const int dm = e0 & 1023;
  const int qlocal = (e0 >> 10) & 255;
  const int b = e0 >> 18;
  const int h = dm >> 6, d0 = dm & 63;
  const int bh = b * 16 + h;
  const int q = slab * 256 + qlocal;

  f32x4 v = *(const f32x4*)(ctxU + ((size_t)b * TT + q) * DM + dm);
#pragma unroll
  for (int ks = 0; ks < 4; ++ks)
    v += *(const f32x4*)(PP + (((size_t)ks * 256 + qlocal) * 64 + bh) * 64 + d0);
  const float invl = 1.0f / l_ws[(size_t)bh * TT + q];
  bf16 o[4];
#pragma unroll
  for (int j = 0; j < 4; ++j) o[j] = __float2bfloat16(v[j] * invl);
  *(short4v*)(ctxB + ((size_t)b * TT + q) * DM + dm) = *(const short4v*)o;
}

// ---------------------------------------------------------------------------
// Output projection: 128x128 LDS-tiled MFMA GEMM, BK=64, 4 waves (2x2).
// ---------------------------------------------------------------------------
__global__ __launch_bounds__(256) void outproj_mfma_kernel(
    const bf16* __restrict__ A,   // [4096][1024] bf16
    const bf16* __restrict__ Bt,  // [1024 n][1024 k] bf16
    float* __restrict__ C) {
  __shared__ __align__(16) bf16 As[128 * 72];
  __shared__ __align__(16) bf16 Bs[128 * 72];
  const int n0 = blockIdx.x * 128;
  const int m0 = blockIdx.y * 128;
  const int tid = threadIdx.x;
  const int w = tid >> 6, lane = tid & 63, l15 = lane & 15, hi = lane >> 4;
  const int wm = w >> 1, wn = w & 1;

  f32x4 acc[4][4];
#pragma unroll
  for (int i = 0; i < 4; ++i)
#pragma unroll
    for (int j = 0; j < 4; ++j) acc[i][j] = (f32x4){0.f, 0.f, 0.f, 0.f};

  const int sr = tid >> 1, sc = (tid & 1) * 32;
  for (int k0 = 0; k0 < 1024; k0 += 64) {
    __syncthreads();
    {
      const bf16* as = A + (size_t)(m0 + sr) * 1024 + k0 + sc;
      const bf16* bs = Bt + (size_t)(n0 + sr) * 1024 + k0 + sc;
#pragma unroll
      for (int ii = 0; ii < 32; ii += 8) {
        *(short8*)(As + sr * 72 + sc + ii) = *(const short8*)(as + ii);
        *(short8*)(Bs + sr * 72 + sc + ii) = *(const short8*)(bs + ii);
      }
    }
    __syncthreads();
#pragma unroll
    for (int kc = 0; kc < 2; ++kc) {
      short8 a[4], b[4];
#pragma unroll
      for (int i = 0; i < 4; ++i)
        a[i] = *(const short8*)(As + (wm * 64 + i * 16 + l15) * 72 + kc * 32 +
                                hi * 8);
#pragma unroll
      for (int j = 0; j < 4; ++j)
        b[j] = *(const short8*)(Bs + (wn * 64 + j * 16 + l15) * 72 + kc * 32 +
                                hi * 8);
#pragma unroll
      for (int i = 0; i < 4; ++i)
#pragma unroll
        for (int j = 0; j < 4; ++j) acc[i][j] = mfma16(a[i], b[j], acc[i][j]);
    }
  }
#pragma unroll
  for (int i = 0; i < 4; ++i) {
#pragma unroll
    for (int jj = 0; jj < 4; ++jj) {
      const size_t row = (size_t)(m0 + wm * 64 + i * 16 + hi * 4 + jj) * 1024;
#pragma unroll
      for (int j = 0; j < 4; ++j)
        C[row + n0 + wn * 64 + j * 16 + l15] = acc[i][j][jj];
    }
  }
}

// ---------------------------------------------------------------------------
extern "C" void kernel_launch(void* const* d_in, const int* in_sizes, int n_in,
                              void* d_out, int out_size, void* d_ws,
                              size_t ws_size, hipStream_t stream) {
  const float* x = (const float*)d_in[0];
  const float* WQ = (const float*)d_in[1];
  const float* WK = (const float*)d_in[2];
  const float* WV = (const float*)d_in[3];
  const float* WZ = (const float*)d_in[4];
  const float* posK = (const float*)d_in[5];
  const float* posV = (const float*)d_in[6];
  const float* maskp = (const float*)d_in[7];
  const int* pos = (const int*)d_in[8];
  float* out = (float*)d_out;

  char* p = (char*)d_ws;
  bf16* Qb = (bf16*)p;        p += (size_t)64 * 1024 * 64 * 2;   // 8 MB
  bf16* Kb = (bf16*)p;        p += (size_t)64 * 1024 * 64 * 2;   // 8 MB
  bf16* Vb = (bf16*)p;        p += (size_t)64 * 1024 * 64 * 2;   // 8 MB
  bf16* Vt = (bf16*)p;        p += (size_t)64 * 64 * 1024 * 2;   // 8 MB
  bf16* posKbf = (bf16*)p;    p += (size_t)2048 * 64 * 2;        // 256 KB
  bf16* WzT = (bf16*)p;       p += (size_t)1024 * 1024 * 2;      // 2 MB
  bf16* Pws = (bf16*)p;       p += (size_t)256 * 64 * 1024 * 2;  // 32 MB
  float* l_ws = (float*)p;    p += (size_t)64 * 1024 * 4;        // 256 KB
  float* ctxU = (float*)p;    p += (size_t)4 * 1024 * 1024 * 4;  // 16 MB
  bf16* ctxB = (bf16*)p;      p += (size_t)4 * 1024 * 1024 * 2;  // 8 MB
  float* PP = (float*)p;      p += (size_t)4 * 256 * 64 * 64 * 4; // 16 MB
  unsigned* pm_ws = (unsigned*)p; p += (size_t)1024 * 1024 * 4;   // 4 MB

  // Aliases (dead-range reuse, safe under stream ordering):
  bf16* xb = (bf16*)ctxU;  // xb dead after qkv; ctxU written later
  bf16* Wt = ctxB;         // Wt dead after qkv; ctxB written later

  xb_kernel<<<2048, 256, 0, stream>>>(x, xb);
  pack_pm_kernel<<<4096, 256, 0, stream>>>(pos, maskp, pm_ws);
  prep_w_kernel<<<dim3(16, 3), 256, 0, stream>>>(WQ, WK, WV, Wt);
  prep_posk_kernel<<<512, 256, 0, stream>>>(posK, posKbf);
  trans_wz_kernel<<<dim3(16, 16), 256, 0, stream>>>(WZ, WzT);
  qkv_mfma_kernel<<<dim3(16, 64), 256, 0, stream>>>(xb, Wt, Qb, Kb, Vb);
  trans_v_kernel<<<dim3(16, 64), 256, 0, stream>>>(Vb, Vt);

  for (int slab = 0; slab < 4; ++slab) {
    score_pv_kernel<<<dim3(64, 16), 256, 0, stream>>>(
        Qb, Kb, posKbf, Vt, pm_ws, Pws, l_ws, ctxU, slab);
    pv_part_kernel<<<dim3(256, 4), 256, 0, stream>>>(Pws, posV, pm_ws, PP,
                                                     slab);
    norm_kernel<<<1024, 256, 0, stream>>>(PP, ctxU, l_ws, ctxB, slab);
  }
  outproj_mfma_kernel<<<dim3(8, 32), 256, 0, stream>>>(ctxB, WzT, out);
}

// Round 12
// 318.676 us; speedup vs baseline: 1.4027x; 1.2864x over previous
//
#include <hip/hip_runtime.h>
#include <hip/hip_bf16.h>

#define BB 4
#define TT 1024
#define DM 1024
#define HH 16

typedef __attribute__((ext_vector_type(8))) short short8;
typedef __attribute__((ext_vector_type(4))) short short4v;
typedef __attribute__((ext_vector_type(4))) float f32x4;
typedef __hip_bfloat16 bf16;

__device__ __forceinline__ f32x4 mfma16(short8 a, short8 b, f32x4 c) {
  return __builtin_amdgcn_mfma_f32_16x16x32_bf16(a, b, c, 0, 0, 0);
}

// ---------------------------------------------------------------------------
// x fp32 -> bf16, 8 elems/thread. grid 2048.
// ---------------------------------------------------------------------------
__global__ __launch_bounds__(256) void xb_kernel(
    const float* __restrict__ x, bf16* __restrict__ xb) {
  const size_t i = ((size_t)blockIdx.x * 256 + threadIdx.x) * 8;
  bf16 tmp[8];
#pragma unroll
  for (int j = 0; j < 8; ++j) tmp[j] = __float2bfloat16(x[i + j]);
  *(short8*)(xb + i) = *(const short8*)tmp;
}

// ---------------------------------------------------------------------------
// pack pos (u16, low) + mask (top 16 bits of fp32, high) into one u32.
// ---------------------------------------------------------------------------
__global__ __launch_bounds__(256) void pack_pm_kernel(
    const int* __restrict__ pos, const float* __restrict__ maskp,
    unsigned* __restrict__ pm) {
  const size_t i = (size_t)blockIdx.x * 256 + threadIdx.x;
  const unsigned mb = __float_as_uint(maskp[i]) & 0xffff0000u;
  pm[i] = mb | (unsigned)pos[i];
}

// ---------------------------------------------------------------------------
// W_{Q,K,V} fp32 [16][64 d][64 e] -> Wt bf16 [3][16][64 e][64 d] (transposed)
// ---------------------------------------------------------------------------
__global__ __launch_bounds__(256) void prep_w_kernel(
    const float* __restrict__ WQ, const float* __restrict__ WK,
    const float* __restrict__ WV, bf16* __restrict__ Wt) {
  __shared__ bf16 tl[64][72];
  const int h = blockIdx.x, m = blockIdx.y;
  const float* W = (m == 0 ? WQ : (m == 1 ? WK : WV)) + h * 4096;
  const int tid = threadIdx.x;
  const int r = tid >> 2, c = (tid & 3) * 16;
#pragma unroll
  for (int i = 0; i < 16; ++i)
    tl[r][c + i] = __float2bfloat16(W[r * 64 + c + i]);
  __syncthreads();
  bf16* o = Wt + ((size_t)(m * 16 + h) * 64 + r) * 64 + c;
#pragma unroll
  for (int i = 0; i < 16; ++i) o[i] = tl[c + i][r];
}

// ---------------------------------------------------------------------------
// prep: posK fp32 [2047][64] -> bf16 [2048][64] (row 2047 zeroed)
// ---------------------------------------------------------------------------
__global__ __launch_bounds__(256) void prep_posk_kernel(
    const float* __restrict__ posK, bf16* __restrict__ posKbf) {
  const int idx = blockIdx.x * 256 + threadIdx.x;
  const int p = idx >> 6, d = idx & 63;
  const float v = (p < 2047) ? posK[(size_t)p * 64 + d] : 0.f;
  posKbf[idx] = __float2bfloat16(v);
}

// ---------------------------------------------------------------------------
// prep: WzT bf16 [n][k] = Wz fp32 [k][n]
// ---------------------------------------------------------------------------
__global__ __launch_bounds__(256) void trans_wz_kernel(
    const float* __restrict__ Wz, bf16* __restrict__ WzT) {
  __shared__ bf16 tile[64][72];
  const int k0 = blockIdx.y * 64, n0 = blockIdx.x * 64;
  const int tid = threadIdx.x;
  const int r = tid >> 2, c = (tid & 3) * 16;
  const float* s = Wz + (size_t)(k0 + r) * 1024 + n0 + c;
#pragma unroll
  for (int i = 0; i < 16; ++i) tile[r][c + i] = __float2bfloat16(s[i]);
  __syncthreads();
  const int n = tid >> 2;
  bf16* o = WzT + (size_t)(n0 + n) * 1024 + k0 + c;
#pragma unroll
  for (int i = 0; i < 16; ++i) o[i] = tile[c + i][n];
}

// ---------------------------------------------------------------------------
// transpose V: [bh][1024][64] bf16 -> Vt [bh][64][1024] bf16
// ---------------------------------------------------------------------------
__global__ __launch_bounds__(256) void trans_v_kernel(
    const bf16* __restrict__ src, bf16* __restrict__ dst) {
  __shared__ bf16 tile[64][72];
  const int bh = blockIdx.y, t0 = blockIdx.x * 64;
  const int tid = threadIdx.x;
  const int r = tid >> 2, c = (tid & 3) * 16;
  const bf16* s = src + ((size_t)bh * TT + t0 + r) * 64 + c;
  *(short8*)(&tile[r][c]) = *(const short8*)(s);
  *(short8*)(&tile[r][c + 8]) = *(const short8*)(s + 8);
  __syncthreads();
  const int d = tid >> 2;
  bf16* o = dst + ((size_t)bh * 64 + d) * TT + t0 + c;
#pragma unroll
  for (int i = 0; i < 16; ++i) o[i] = tile[c + i][d];
}

// ---------------------------------------------------------------------------
// QKV projection via MFMA. grid (16 ttiles, 64 bh), block 256 (4 waves).
// ---------------------------------------------------------------------------
__global__ __launch_bounds__(256) void qkv_mfma_kernel(
    const bf16* __restrict__ xb, const bf16* __restrict__ Wt,
    bf16* __restrict__ Qg, bf16* __restrict__ Kg, bf16* __restrict__ Vg) {
  __shared__ __align__(16) bf16 xs[64 * 72];
  const int bh = blockIdx.y;
  const int b = bh >> 4, h = bh & 15;
  const int t0 = blockIdx.x * 64;
  const int tid = threadIdx.x;
  const int w = tid >> 6, lane = tid & 63, l15 = lane & 15, hi = lane >> 4;

  {
    const int r = tid >> 2, c = (tid & 3) * 16;
    const bf16* src = xb + ((size_t)b * TT + t0 + r) * DM + h * 64 + c;
    *(short8*)(xs + r * 72 + c) = *(const short8*)(src);
    *(short8*)(xs + r * 72 + c + 8) = *(const short8*)(src + 8);
  }
  __syncthreads();

  f32x4 aQ[4] = {{0.f, 0.f, 0.f, 0.f}, {0.f, 0.f, 0.f, 0.f},
                 {0.f, 0.f, 0.f, 0.f}, {0.f, 0.f, 0.f, 0.f}};
  f32x4 aK[4] = {{0.f, 0.f, 0.f, 0.f}, {0.f, 0.f, 0.f, 0.f},
                 {0.f, 0.f, 0.f, 0.f}, {0.f, 0.f, 0.f, 0.f}};
  f32x4 aV[4] = {{0.f, 0.f, 0.f, 0.f}, {0.f, 0.f, 0.f, 0.f},
                 {0.f, 0.f, 0.f, 0.f}, {0.f, 0.f, 0.f, 0.f}};
  const bf16* WtQ = Wt + (size_t)h * 4096;
  const bf16* WtK = Wt + (size_t)(16 + h) * 4096;
  const bf16* WtV = Wt + (size_t)(32 + h) * 4096;
#pragma unroll
  for (int kc = 0; kc < 2; ++kc) {
    const short8 a =
        *(const short8*)(xs + (w * 16 + l15) * 72 + kc * 32 + hi * 8);
#pragma unroll
    for (int nt = 0; nt < 4; ++nt) {
      const size_t wo = (size_t)(nt * 16 + l15) * 64 + kc * 32 + hi * 8;
      aQ[nt] = mfma16(a, *(const short8*)(WtQ + wo), aQ[nt]);
      aK[nt] = mfma16(a, *(const short8*)(WtK + wo), aK[nt]);
      aV[nt] = mfma16(a, *(const short8*)(WtV + wo), aV[nt]);
    }
  }
  const int t = t0 + w * 16 + hi * 4;
#pragma unroll
  for (int nt = 0; nt < 4; ++nt) {
#pragma unroll
    for (int j = 0; j < 4; ++j) {
      const size_t o = ((size_t)bh * TT + t + j) * 64 + nt * 16 + l15;
      Qg[o] = __float2bfloat16(aQ[nt][j]);
      Kg[o] = __float2bfloat16(aK[nt][j]);
      Vg[o] = __float2bfloat16(aV[nt][j]);
    }
  }
}

// ---------------------------------------------------------------------------
// Fused score kernel v8: 32 q-rows per block (L1-byte amortization).
//  Theory: kernel is L1-return-BW bound (~640 KB VMEM bytes/block at 16 q).
//  Doubling q per block keeps K/Vt/posKbf bytes constant while doubling
//  output -> per-CU bytes drop 1.8x. K/Vt/posK register frags are reused
//  for both q-halves (2x MFMA per load).
// grid (64 bh, 8 qt), block 256 (4 waves), 2 blocks/CU (75 KB LDS).
// ---------------------------------------------------------------------------
#define QP8_S 2052
#define PSM_S 72

__global__ __launch_bounds__(256, 2) void score_pv_kernel(
    const bf16* __restrict__ Qb,
    const bf16* __restrict__ Kb,
    const bf16* __restrict__ posKbf,
    const bf16* __restrict__ Vt,
    const unsigned* __restrict__ pm,   // packed mask|pos
    bf16* __restrict__ Pws,        // [256 qlocal][64 bh][1024 k]
    float* __restrict__ l_ws,      // [64 bh][1024 q]
    float* __restrict__ ctxU,      // [b][t][1024] fp32 unnormalized
    int slab) {
  __shared__ __align__(16) unsigned char QPsh[32 * QP8_S];  // 65664 B
  __shared__ __align__(16) bf16 Psm[2][32 * PSM_S];         // 9216 B
  __shared__ float lred[4][32];                             // 512 B

  const int bh = blockIdx.x;
  const int qt = blockIdx.y;           // 0..7
  const int qlocal0 = qt * 32;
  const int qg0 = slab * 256 + qlocal0;
  const int tid = threadIdx.x;
  const int w = tid >> 6;
  const int lane = tid & 63;
  const int l15 = lane & 15;
  const int hi = lane >> 4;

  // Q fragments for both q-halves
  const bf16* Qrow0 = Qb + ((size_t)bh * TT + qg0 + l15) * 64 + hi * 8;
  const bf16* Qrow1 = Qrow0 + 16 * 64;
  const short8 aq0 = *(const short8*)(Qrow0);
  const short8 aq1 = *(const short8*)(Qrow0 + 32);
  const short8 aq2 = *(const short8*)(Qrow1);
  const short8 aq3 = *(const short8*)(Qrow1 + 32);

  // ---- QP phase: wave w covers p-tiles w*32..w*32+31; both q-halves per
  // posK load; fp8 store; 2-stage register pipeline.
  {
    const bf16* Kp0 = posKbf + ((size_t)(w * 32 * 16 + l15)) * 64 + hi * 8;
    short8 qb0 = *(const short8*)(Kp0);
    short8 qb1 = *(const short8*)(Kp0 + 32);
    for (int i = 0; i < 32; ++i) {
      const int pt = w * 32 + i;
      const short8 cb0 = qb0, cb1 = qb1;
      {
        const int ptn = w * 32 + ((i + 1) & 31);
        const bf16* Kpn = posKbf + ((size_t)(ptn * 16 + l15)) * 64 + hi * 8;
        qb0 = *(const short8*)(Kpn);
        qb1 = *(const short8*)(Kpn + 32);
      }
      f32x4 alo = {0.f, 0.f, 0.f, 0.f};
      alo = mfma16(aq0, cb0, alo);
      alo = mfma16(aq1, cb1, alo);
      f32x4 ahi = {0.f, 0.f, 0.f, 0.f};
      ahi = mfma16(aq2, cb0, ahi);
      ahi = mfma16(aq3, cb1, ahi);
      const int off = pt * 16 + l15;
      {
        const int p01 = __builtin_amdgcn_cvt_pk_fp8_f32(alo[0], alo[1], 0, false);
        const int p23 = __builtin_amdgcn_cvt_pk_fp8_f32(alo[2], alo[3], 0, false);
        QPsh[(hi * 4 + 0) * QP8_S + off] = (unsigned char)(p01 & 0xff);
        QPsh[(hi * 4 + 1) * QP8_S + off] = (unsigned char)((p01 >> 8) & 0xff);
        QPsh[(hi * 4 + 2) * QP8_S + off] = (unsigned char)(p23 & 0xff);
        QPsh[(hi * 4 + 3) * QP8_S + off] = (unsigned char)((p23 >> 8) & 0xff);
      }
      {
        const int p01 = __builtin_amdgcn_cvt_pk_fp8_f32(ahi[0], ahi[1], 0, false);
        const int p23 = __builtin_amdgcn_cvt_pk_fp8_f32(ahi[2], ahi[3], 0, false);
        QPsh[(16 + hi * 4 + 0) * QP8_S + off] = (unsigned char)(p01 & 0xff);
        QPsh[(16 + hi * 4 + 1) * QP8_S + off] = (unsigned char)((p01 >> 8) & 0xff);
        QPsh[(16 + hi * 4 + 2) * QP8_S + off] = (unsigned char)(p23 & 0xff);
        QPsh[(16 + hi * 4 + 3) * QP8_S + off] = (unsigned char)((p23 >> 8) & 0xff);
      }
    }
  }
  __syncthreads();

  // wave w owns PV output d-tile [w*16, w*16+16) for all 32 q
  f32x4 acc_lo = {0.f, 0.f, 0.f, 0.f};
  f32x4 acc_hi = {0.f, 0.f, 0.f, 0.f};
  float lp[8] = {0.f, 0.f, 0.f, 0.f, 0.f, 0.f, 0.f, 0.f};
  const int kk = w * 16 + l15;
  const bf16* Kbh = Kb + (size_t)bh * TT * 64;
  const bf16* Vtrow = Vt + ((size_t)bh * 64 + w * 16 + l15) * TT;

  // prologue: stage tile 0 operands in registers
  short8 nb0 = *(const short8*)(Kbh + (size_t)kk * 64 + hi * 8);
  short8 nb1 = *(const short8*)(Kbh + (size_t)kk * 64 + 32 + hi * 8);
  short8 nv0 = *(const short8*)(Vtrow + hi * 8);
  short8 nv1 = *(const short8*)(Vtrow + 32 + hi * 8);
  unsigned npm[8];
#pragma unroll
  for (int j = 0; j < 4; ++j) {
    npm[j] = pm[(size_t)(qg0 + hi * 4 + j) * TT + kk];
    npm[4 + j] = pm[(size_t)(qg0 + 16 + hi * 4 + j) * TT + kk];
  }

  for (int it = 0; it < 16; ++it) {
    const int k0 = it * 64;
    bf16* PsmC = &Psm[it & 1][0];
    const short8 cb0 = nb0, cb1 = nb1, cv0 = nv0, cv1 = nv1;
    unsigned cpm[8];
#pragma unroll
    for (int j = 0; j < 8; ++j) cpm[j] = npm[j];
    {
      const int k0n = ((it + 1) & 15) * 64;
      nb0 = *(const short8*)(Kbh + (size_t)(k0n + kk) * 64 + hi * 8);
      nb1 = *(const short8*)(Kbh + (size_t)(k0n + kk) * 64 + 32 + hi * 8);
      nv0 = *(const short8*)(Vtrow + k0n + hi * 8);
      nv1 = *(const short8*)(Vtrow + k0n + 32 + hi * 8);
#pragma unroll
      for (int j = 0; j < 4; ++j) {
        npm[j] = pm[(size_t)(qg0 + hi * 4 + j) * TT + k0n + kk];
        npm[4 + j] = pm[(size_t)(qg0 + 16 + hi * 4 + j) * TT + k0n + kk];
      }
    }
    // content scores for both q-halves from shared K frags
    f32x4 slo = {0.f, 0.f, 0.f, 0.f};
    slo = mfma16(aq0, cb0, slo);
    slo = mfma16(aq1, cb1, slo);
    f32x4 shi = {0.f, 0.f, 0.f, 0.f};
    shi = mfma16(aq2, cb0, shi);
    shi = mfma16(aq3, cb1, shi);
    // + QP[pos] (fp8 LDS gather) + mask, *0.125, exp -> Psm[cur]
#pragma unroll
    for (int half = 0; half < 2; ++half) {
      const f32x4 sv4 = half ? shi : slo;
#pragma unroll
      for (int j = 0; j < 4; ++j) {
        const int q = half * 16 + hi * 4 + j;
        const unsigned pmv = cpm[half * 4 + j];
        const float qp = __builtin_amdgcn_cvt_f32_fp8(
            (int)QPsh[q * QP8_S + (pmv & 0xffffu)], 0);
        const float sv =
            (sv4[j] + qp + __uint_as_float(pmv & 0xffff0000u)) * 0.125f;
        const float pe = __expf(sv);
        lp[half * 4 + j] += pe;
        PsmC[q * PSM_S + kk] = __float2bfloat16(pe);
      }
    }
    __syncthreads();
    // store P tile (32 q x 64 k) to global, coalesced via LDS
    {
      const int r = tid >> 3, c = (tid & 7) * 8;
      *(short8*)(Pws + ((size_t)(qlocal0 + r) * 64 + bh) * TT + k0 + c) =
          *(const short8*)(PsmC + r * PSM_S + c);
    }
    // PV MFMAs: wave w's d-tile, both q-halves, shared Vt frags
    {
      const short8 pa0 = *(const short8*)(PsmC + l15 * PSM_S + hi * 8);
      acc_lo = mfma16(pa0, cv0, acc_lo);
      const short8 pa1 = *(const short8*)(PsmC + l15 * PSM_S + 32 + hi * 8);
      acc_lo = mfma16(pa1, cv1, acc_lo);
      const short8 pb0 = *(const short8*)(PsmC + (16 + l15) * PSM_S + hi * 8);
      acc_hi = mfma16(pb0, cv0, acc_hi);
      const short8 pb1 =
          *(const short8*)(PsmC + (16 + l15) * PSM_S + 32 + hi * 8);
      acc_hi = mfma16(pb1, cv1, acc_hi);
    }
  }

  // l row-sums: reduce over l15 lanes, then across waves
#pragma unroll
  for (int j = 0; j < 8; ++j) {
    float v = lp[j];
    v += __shfl_xor(v, 1);
    v += __shfl_xor(v, 2);
    v += __shfl_xor(v, 4);
    v += __shfl_xor(v, 8);
    lp[j] = v;
  }
  __syncthreads();
  if (l15 == 0) {
#pragma unroll
    for (int j = 0; j < 4; ++j) {
      lred[w][hi * 4 + j] = lp[j];
      lred[w][16 + hi * 4 + j] = lp[4 + j];
    }
  }
  __syncthreads();
  if (tid < 32) {
    const float l = lred[0][tid] + lred[1][tid] + lred[2][tid] + lred[3][tid];
    l_ws[(size_t)bh * TT + qg0 + tid] = l;
  }
  // ctxU scatter: wave w owns d-range [w*16, w*16+16); 32 q rows
  {
    const int b = bh >> 4, h = bh & 15;
#pragma unroll
    for (int j = 0; j < 4; ++j) {
      const int q = hi * 4 + j;
      ctxU[((size_t)b * TT + qg0 + q) * DM + h * 64 + w * 16 + l15] = acc_lo[j];
      ctxU[((size_t)b * TT + qg0 + 16 + q) * DM + h * 64 + w * 16 + l15] =
          acc_hi[j];
    }
  }
}

// ---------------------------------------------------------------------------
// PV partial kernel (k-split x4): grid (256 q, 4 ks), block 256.
// ---------------------------------------------------------------------------
#define PVT_S 72
__global__ __launch_bounds__(256) void pv_part_kernel(
    const bf16* __restrict__ Pws,
    const float* __restrict__ posV,
    const unsigned* __restrict__ pm,
    float* __restrict__ PP,   // [4][256][64][64] fp32
    int slab) {
  __shared__ __align__(16) bf16 PVt[2][64 * PVT_S];
  __shared__ unsigned short possh[256];

  const int qlocal = blockIdx.x;
  const int q = slab * 256 + qlocal;
  const int ks = blockIdx.y;
  const int kbase = ks * 256;
  const int tid = threadIdx.x;
  const int w = tid >> 6, lane = tid & 63, l15 = lane & 15, hi = lane >> 4;

  possh[tid] = (unsigned short)(pm[(size_t)q * TT + kbase + tid] & 0xffffu);
  __syncthreads();

  f32x4 acc[4] = {{0.f, 0.f, 0.f, 0.f}, {0.f, 0.f, 0.f, 0.f},
                  {0.f, 0.f, 0.f, 0.f}, {0.f, 0.f, 0.f, 0.f}};
  const bf16* Prow = Pws + ((size_t)qlocal * 64 + w * 16 + l15) * TT;

  for (int it = 0; it < 4; ++it) {
    const int k0 = kbase + it * 64;
    bf16* pvt = &PVt[it & 1][0];
    {
      const int kr = lane;
      const int dc = w * 16;
      const int p = possh[it * 64 + kr];
      const float* src = posV + (size_t)p * 64 + dc;
#pragma unroll
      for (int ii = 0; ii < 16; ii += 4) {
        const f32x4 v = *(const f32x4*)(src + ii);
        pvt[(dc + ii + 0) * PVT_S + kr] = __float2bfloat16(v[0]);
        pvt[(dc + ii + 1) * PVT_S + kr] = __float2bfloat16(v[1]);
        pvt[(dc + ii + 2) * PVT_S + kr] = __float2bfloat16(v[2]);
        pvt[(dc + ii + 3) * PVT_S + kr] = __float2bfloat16(v[3]);
      }
    }
    __syncthreads();
#pragma unroll
    for (int kc = 0; kc < 2; ++kc) {
      const short8 a = *(const short8*)(Prow + k0 + kc * 32 + hi * 8);
#pragma unroll
      for (int nt = 0; nt < 4; ++nt) {
        const short8 bv =
            *(const short8*)(pvt + (nt * 16 + l15) * PVT_S + kc * 32 + hi * 8);
        acc[nt] = mfma16(a, bv, acc[nt]);
      }
    }
  }

  const int bh0 = w * 16 + hi * 4;
#pragma unroll
  for (int j = 0; j < 4; ++j) {
    const int bh = bh0 + j;
    float* o = PP + (((size_t)ks * 256 + qlocal) * 64 + bh) * 64;
#pragma unroll
    for (int nt = 0; nt < 4; ++nt) o[nt * 16 + l15] = acc[nt][j];
  }
}

// ---------------------------------------------------------------------------
// Normalize: ctxB = (ctxU + sum_ks PP) / l. grid 1024, block 256.
// ---------------------------------------------------------------------------
__global__ __launch_bounds__(256) void norm_kernel(
    const float* __restrict__ PP,
    const float* __restrict__ ctxU,
    const float* __restrict__ l_ws,
    bf16* __restrict__ ctxB,
    int slab) {
  const int i4 = blockIdx.x * 256 + threadIdx.x;  // 0..262143
  const int e0 = i4 * 4;
  const int dm = e0 & 1023;
  const int qlocal = (e0 >> 10) & 255;
  const int b = e0 >> 18;
  const int h = dm >> 6, d0 = dm & 63;
  const int bh = b * 16 + h;
  const int q = slab * 256 + qlocal;

  f32x4 v = *(const f32x4*)(ctxU + ((size_t)b * TT + q) * DM + dm);
#pragma unroll
  for (int ks = 0; ks < 4; ++ks)
    v += *(const f32x4*)(PP + (((size_t)ks * 256 + qlocal) * 64 + bh) * 64 + d0);
  const float invl = 1.0f / l_ws[(size_t)bh * TT + q];
  bf16 o[4];
#pragma unroll
  for (int j = 0; j < 4; ++j) o[j] = __float2bfloat16(v[j] * invl);
  *(short4v*)(ctxB + ((size_t)b * TT + q) * DM + dm) = *(const short4v*)o;
}

// ---------------------------------------------------------------------------
// Output projection: 128x128 LDS-tiled MFMA GEMM, BK=64, 4 waves (2x2).
// ---------------------------------------------------------------------------
__global__ __launch_bounds__(256) void outproj_mfma_kernel(
    const bf16* __restrict__ A,   // [4096][1024] bf16
    const bf16* __restrict__ Bt,  // [1024 n][1024 k] bf16
    float* __restrict__ C) {
  __shared__ __align__(16) bf16 As[128 * 72];
  __shared__ __align__(16) bf16 Bs[128 * 72];
  const int n0 = blockIdx.x * 128;
  const int m0 = blockIdx.y * 128;
  const int tid = threadIdx.x;
  const int w = tid >> 6, lane = tid & 63, l15 = lane & 15, hi = lane >> 4;
  const int wm = w >> 1, wn = w & 1;

  f32x4 acc[4][4];
#pragma unroll
  for (int i = 0; i < 4; ++i)
#pragma unroll
    for (int j = 0; j < 4; ++j) acc[i][j] = (f32x4){0.f, 0.f, 0.f, 0.f};

  const int sr = tid >> 1, sc = (tid & 1) * 32;
  for (int k0 = 0; k0 < 1024; k0 += 64) {
    __syncthreads();
    {
      const bf16* as = A + (size_t)(m0 + sr) * 1024 + k0 + sc;
      const bf16* bs = Bt + (size_t)(n0 + sr) * 1024 + k0 + sc;
#pragma unroll
      for (int ii = 0; ii < 32; ii += 8) {
        *(short8*)(As + sr * 72 + sc + ii) = *(const short8*)(as + ii);
        *(short8*)(Bs + sr * 72 + sc + ii) = *(const short8*)(bs + ii);
      }
    }
    __syncthreads();
#pragma unroll
    for (int kc = 0; kc < 2; ++kc) {
      short8 a[4], b[4];
#pragma unroll
      for (int i = 0; i < 4; ++i)
        a[i] = *(const short8*)(As + (wm * 64 + i * 16 + l15) * 72 + kc * 32 +
                                hi * 8);
#pragma unroll
      for (int j = 0; j < 4; ++j)
        b[j] = *(const short8*)(Bs + (wn * 64 + j * 16 + l15) * 72 + kc * 32 +
                                hi * 8);
#pragma unroll
      for (int i = 0; i < 4; ++i)
#pragma unroll
        for (int j = 0; j < 4; ++j) acc[i][j] = mfma16(a[i], b[j], acc[i][j]);
    }
  }
#pragma unroll
  for (int i = 0; i < 4; ++i) {
#pragma unroll
    for (int jj = 0; jj < 4; ++jj) {
      const size_t row = (size_t)(m0 + wm * 64 + i * 16 + hi * 4 + jj) * 1024;
#pragma unroll
      for (int j = 0; j < 4; ++j)
        C[row + n0 + wn * 64 + j * 16 + l15] = acc[i][j][jj];
    }
  }
}

// ---------------------------------------------------------------------------
extern "C" void kernel_launch(void* const* d_in, const int* in_sizes, int n_in,
                              void* d_out, int out_size, void* d_ws,
                              size_t ws_size, hipStream_t stream) {
  const float* x = (const float*)d_in[0];
  const float* WQ = (const float*)d_in[1];
  const float* WK = (const float*)d_in[2];
  const float* WV = (const float*)d_in[3];
  const float* WZ = (const float*)d_in[4];
  const float* posK = (const float*)d_in[5];
  const float* posV = (const float*)d_in[6];
  const float* maskp = (const float*)d_in[7];
  const int* pos = (const int*)d_in[8];
  float* out = (float*)d_out;

  char* p = (char*)d_ws;
  bf16* Qb = (bf16*)p;        p += (size_t)64 * 1024 * 64 * 2;   // 8 MB
  bf16* Kb = (bf16*)p;        p += (size_t)64 * 1024 * 64 * 2;   // 8 MB
  bf16* Vb = (bf16*)p;        p += (size_t)64 * 1024 * 64 * 2;   // 8 MB
  bf16* Vt = (bf16*)p;        p += (size_t)64 * 64 * 1024 * 2;   // 8 MB
  bf16* posKbf = (bf16*)p;    p += (size_t)2048 * 64 * 2;        // 256 KB
  bf16* WzT = (bf16*)p;       p += (size_t)1024 * 1024 * 2;      // 2 MB
  bf16* Pws = (bf16*)p;       p += (size_t)256 * 64 * 1024 * 2;  // 32 MB
  float* l_ws = (float*)p;    p += (size_t)64 * 1024 * 4;        // 256 KB
  float* ctxU = (float*)p;    p += (size_t)4 * 1024 * 1024 * 4;  // 16 MB
  bf16* ctxB = (bf16*)p;      p += (size_t)4 * 1024 * 1024 * 2;  // 8 MB
  float* PP = (float*)p;      p += (size_t)4 * 256 * 64 * 64 * 4; // 16 MB
  unsigned* pm_ws = (unsigned*)p; p += (size_t)1024 * 1024 * 4;   // 4 MB

  // Aliases (dead-range reuse, safe under stream ordering):
  bf16* xb = (bf16*)ctxU;  // xb dead after qkv; ctxU written later
  bf16* Wt = ctxB;         // Wt dead after qkv; ctxB written later

  xb_kernel<<<2048, 256, 0, stream>>>(x, xb);
  pack_pm_kernel<<<4096, 256, 0, stream>>>(pos, maskp, pm_ws);
  prep_w_kernel<<<dim3(16, 3), 256, 0, stream>>>(WQ, WK, WV, Wt);
  prep_posk_kernel<<<512, 256, 0, stream>>>(posK, posKbf);
  trans_wz_kernel<<<dim3(16, 16), 256, 0, stream>>>(WZ, WzT);
  qkv_mfma_kernel<<<dim3(16, 64), 256, 0, stream>>>(xb, Wt, Qb, Kb, Vb);
  trans_v_kernel<<<dim3(16, 64), 256, 0, stream>>>(Vb, Vt);

  for (int slab = 0; slab < 4; ++slab) {
    score_pv_kernel<<<dim3(64, 8), 256, 0, stream>>>(
        Qb, Kb, posKbf, Vt, pm_ws, Pws, l_ws, ctxU, slab);
    pv_part_kernel<<<dim3(256, 4), 256, 0, stream>>>(Pws, posV, pm_ws, PP,
                                                     slab);
    norm_kernel<<<1024, 256, 0, stream>>>(PP, ctxU, l_ws, ctxB, slab);
  }
  outproj_mfma_kernel<<<dim3(8, 32), 256, 0, stream>>>(ctxB, WzT, out);
}

// Round 13
// 283.971 us; speedup vs baseline: 1.5741x; 1.1222x over previous
//
#include <hip/hip_runtime.h>
#include <hip/hip_bf16.h>

#define BB 4
#define TT 1024
#define DM 1024
#define HH 16

typedef __attribute__((ext_vector_type(8))) short short8;
typedef __attribute__((ext_vector_type(4))) short short4v;
typedef __attribute__((ext_vector_type(4))) float f32x4;
typedef __hip_bfloat16 bf16;

__device__ __forceinline__ f32x4 mfma16(short8 a, short8 b, f32x4 c) {
  return __builtin_amdgcn_mfma_f32_16x16x32_bf16(a, b, c, 0, 0, 0);
}

// ---------------------------------------------------------------------------
// x fp32 -> bf16, 8 elems/thread. grid 2048.
// ---------------------------------------------------------------------------
__global__ __launch_bounds__(256) void xb_kernel(
    const float* __restrict__ x, bf16* __restrict__ xb) {
  const size_t i = ((size_t)blockIdx.x * 256 + threadIdx.x) * 8;
  bf16 tmp[8];
#pragma unroll
  for (int j = 0; j < 8; ++j) tmp[j] = __float2bfloat16(x[i + j]);
  *(short8*)(xb + i) = *(const short8*)tmp;
}

// ---------------------------------------------------------------------------
// pack pos (u16, low) + mask (top 16 bits of fp32, high) into one u32.
// ---------------------------------------------------------------------------
__global__ __launch_bounds__(256) void pack_pm_kernel(
    const int* __restrict__ pos, const float* __restrict__ maskp,
    unsigned* __restrict__ pm) {
  const size_t i = (size_t)blockIdx.x * 256 + threadIdx.x;
  const unsigned mb = __float_as_uint(maskp[i]) & 0xffff0000u;
  pm[i] = mb | (unsigned)pos[i];
}

// ---------------------------------------------------------------------------
// W_{Q,K,V} fp32 [16][64 d][64 e] -> Wt bf16 [3][16][64 e][64 d] (transposed)
// ---------------------------------------------------------------------------
__global__ __launch_bounds__(256) void prep_w_kernel(
    const float* __restrict__ WQ, const float* __restrict__ WK,
    const float* __restrict__ WV, bf16* __restrict__ Wt) {
  __shared__ bf16 tl[64][72];
  const int h = blockIdx.x, m = blockIdx.y;
  const float* W = (m == 0 ? WQ : (m == 1 ? WK : WV)) + h * 4096;
  const int tid = threadIdx.x;
  const int r = tid >> 2, c = (tid & 3) * 16;
#pragma unroll
  for (int i = 0; i < 16; ++i)
    tl[r][c + i] = __float2bfloat16(W[r * 64 + c + i]);
  __syncthreads();
  bf16* o = Wt + ((size_t)(m * 16 + h) * 64 + r) * 64 + c;
#pragma unroll
  for (int i = 0; i < 16; ++i) o[i] = tl[c + i][r];
}

// ---------------------------------------------------------------------------
// prep: posK fp32 [2047][64] -> bf16 [2048][64] (row 2047 zeroed)
// ---------------------------------------------------------------------------
__global__ __launch_bounds__(256) void prep_posk_kernel(
    const float* __restrict__ posK, bf16* __restrict__ posKbf) {
  const int idx = blockIdx.x * 256 + threadIdx.x;
  const int p = idx >> 6, d = idx & 63;
  const float v = (p < 2047) ? posK[(size_t)p * 64 + d] : 0.f;
  posKbf[idx] = __float2bfloat16(v);
}

// ---------------------------------------------------------------------------
// prep: WzT bf16 [n][k] = Wz fp32 [k][n]
// ---------------------------------------------------------------------------
__global__ __launch_bounds__(256) void trans_wz_kernel(
    const float* __restrict__ Wz, bf16* __restrict__ WzT) {
  __shared__ bf16 tile[64][72];
  const int k0 = blockIdx.y * 64, n0 = blockIdx.x * 64;
  const int tid = threadIdx.x;
  const int r = tid >> 2, c = (tid & 3) * 16;
  const float* s = Wz + (size_t)(k0 + r) * 1024 + n0 + c;
#pragma unroll
  for (int i = 0; i < 16; ++i) tile[r][c + i] = __float2bfloat16(s[i]);
  __syncthreads();
  const int n = tid >> 2;
  bf16* o = WzT + (size_t)(n0 + n) * 1024 + k0 + c;
#pragma unroll
  for (int i = 0; i < 16; ++i) o[i] = tile[c + i][n];
}

// ---------------------------------------------------------------------------
// transpose V: [bh][1024][64] bf16 -> Vt [bh][64][1024] bf16
// ---------------------------------------------------------------------------
__global__ __launch_bounds__(256) void trans_v_kernel(
    const bf16* __restrict__ src, bf16* __restrict__ dst) {
  __shared__ bf16 tile[64][72];
  const int bh = blockIdx.y, t0 = blockIdx.x * 64;
  const int tid = threadIdx.x;
  const int r = tid >> 2, c = (tid & 3) * 16;
  const bf16* s = src + ((size_t)bh * TT + t0 + r) * 64 + c;
  *(short8*)(&tile[r][c]) = *(const short8*)(s);
  *(short8*)(&tile[r][c + 8]) = *(const short8*)(s + 8);
  __syncthreads();
  const int d = tid >> 2;
  bf16* o = dst + ((size_t)bh * 64 + d) * TT + t0 + c;
#pragma unroll
  for (int i = 0; i < 16; ++i) o[i] = tile[c + i][d];
}

// ---------------------------------------------------------------------------
// QKV projection via MFMA. grid (16 ttiles, 64 bh), block 256 (4 waves).
// ---------------------------------------------------------------------------
__global__ __launch_bounds__(256) void qkv_mfma_kernel(
    const bf16* __restrict__ xb, const bf16* __restrict__ Wt,
    bf16* __restrict__ Qg, bf16* __restrict__ Kg, bf16* __restrict__ Vg) {
  __shared__ __align__(16) bf16 xs[64 * 72];
  const int bh = blockIdx.y;
  const int b = bh >> 4, h = bh & 15;
  const int t0 = blockIdx.x * 64;
  const int tid = threadIdx.x;
  const int w = tid >> 6, lane = tid & 63, l15 = lane & 15, hi = lane >> 4;

  {
    const int r = tid >> 2, c = (tid & 3) * 16;
    const bf16* src = xb + ((size_t)b * TT + t0 + r) * DM + h * 64 + c;
    *(short8*)(xs + r * 72 + c) = *(const short8*)(src);
    *(short8*)(xs + r * 72 + c + 8) = *(const short8*)(src + 8);
  }
  __syncthreads();

  f32x4 aQ[4] = {{0.f, 0.f, 0.f, 0.f}, {0.f, 0.f, 0.f, 0.f},
                 {0.f, 0.f, 0.f, 0.f}, {0.f, 0.f, 0.f, 0.f}};
  f32x4 aK[4] = {{0.f, 0.f, 0.f, 0.f}, {0.f, 0.f, 0.f, 0.f},
                 {0.f, 0.f, 0.f, 0.f}, {0.f, 0.f, 0.f, 0.f}};
  f32x4 aV[4] = {{0.f, 0.f, 0.f, 0.f}, {0.f, 0.f, 0.f, 0.f},
                 {0.f, 0.f, 0.f, 0.f}, {0.f, 0.f, 0.f, 0.f}};
  const bf16* WtQ = Wt + (size_t)h * 4096;
  const bf16* WtK = Wt + (size_t)(16 + h) * 4096;
  const bf16* WtV = Wt + (size_t)(32 + h) * 4096;
#pragma unroll
  for (int kc = 0; kc < 2; ++kc) {
    const short8 a =
        *(const short8*)(xs + (w * 16 + l15) * 72 + kc * 32 + hi * 8);
#pragma unroll
    for (int nt = 0; nt < 4; ++nt) {
      const size_t wo = (size_t)(nt * 16 + l15) * 64 + kc * 32 + hi * 8;
      aQ[nt] = mfma16(a, *(const short8*)(WtQ + wo), aQ[nt]);
      aK[nt] = mfma16(a, *(const short8*)(WtK + wo), aK[nt]);
      aV[nt] = mfma16(a, *(const short8*)(WtV + wo), aV[nt]);
    }
  }
  const int t = t0 + w * 16 + hi * 4;
#pragma unroll
  for (int nt = 0; nt < 4; ++nt) {
#pragma unroll
    for (int j = 0; j < 4; ++j) {
      const size_t o = ((size_t)bh * TT + t + j) * 64 + nt * 16 + l15;
      Qg[o] = __float2bfloat16(aQ[nt][j]);
      Kg[o] = __float2bfloat16(aK[nt][j]);
      Vg[o] = __float2bfloat16(aV[nt][j]);
    }
  }
}

// ---------------------------------------------------------------------------
// Fused score kernel v9: 64 q-rows per block (max L1-byte amortization).
//  Per-CU VMEM bytes: v8 1.42 MB -> 0.78 MB. K/Vt/posKbf/pm register frags
//  feed FOUR q-halves. LDS ~151 KB -> 1 block/CU (grid 256 = #CUs).
// grid (64 bh, 4 qt), block 256 (4 waves).
// ---------------------------------------------------------------------------
#define QP8_S 2052
#define PSM_S 72

__global__ __launch_bounds__(256, 1) void score_pv_kernel(
    const bf16* __restrict__ Qb,
    const bf16* __restrict__ Kb,
    const bf16* __restrict__ posKbf,
    const bf16* __restrict__ Vt,
    const unsigned* __restrict__ pm,   // packed mask|pos
    bf16* __restrict__ Pws,        // [256 qlocal][64 bh][1024 k]
    float* __restrict__ l_ws,      // [64 bh][1024 q]
    float* __restrict__ ctxU,      // [b][t][1024] fp32 unnormalized
    int slab) {
  __shared__ __align__(16) unsigned char QPsh[64 * QP8_S];  // 131328 B
  __shared__ __align__(16) bf16 Psm[2][64 * PSM_S];         // 18432 B
  __shared__ float lred[4][64];                             // 1024 B

  const int bh = blockIdx.x;
  const int qt = blockIdx.y;           // 0..3
  const int qlocal0 = qt * 64;
  const int qg0 = slab * 256 + qlocal0;
  const int tid = threadIdx.x;
  const int w = tid >> 6;
  const int lane = tid & 63;
  const int l15 = lane & 15;
  const int hi = lane >> 4;

  // Q fragments for 4 q-halves (h*16 rows each)
  short8 aqA[4], aqB[4];
#pragma unroll
  for (int h = 0; h < 4; ++h) {
    const bf16* Qrow =
        Qb + ((size_t)bh * TT + qg0 + h * 16 + l15) * 64 + hi * 8;
    aqA[h] = *(const short8*)(Qrow);
    aqB[h] = *(const short8*)(Qrow + 32);
  }

  // ---- QP phase: wave w covers p-tiles w*32..w*32+31; 4 q-halves per
  // posK load; fp8 store; 2-stage register pipeline.
  {
    const bf16* Kp0 = posKbf + ((size_t)(w * 32 * 16 + l15)) * 64 + hi * 8;
    short8 qb0 = *(const short8*)(Kp0);
    short8 qb1 = *(const short8*)(Kp0 + 32);
    for (int i = 0; i < 32; ++i) {
      const int pt = w * 32 + i;
      const short8 cb0 = qb0, cb1 = qb1;
      {
        const int ptn = w * 32 + ((i + 1) & 31);
        const bf16* Kpn = posKbf + ((size_t)(ptn * 16 + l15)) * 64 + hi * 8;
        qb0 = *(const short8*)(Kpn);
        qb1 = *(const short8*)(Kpn + 32);
      }
      const int off = pt * 16 + l15;
#pragma unroll
      for (int h = 0; h < 4; ++h) {
        f32x4 a4 = {0.f, 0.f, 0.f, 0.f};
        a4 = mfma16(aqA[h], cb0, a4);
        a4 = mfma16(aqB[h], cb1, a4);
        const int p01 = __builtin_amdgcn_cvt_pk_fp8_f32(a4[0], a4[1], 0, false);
        const int p23 = __builtin_amdgcn_cvt_pk_fp8_f32(a4[2], a4[3], 0, false);
        const int qr = h * 16 + hi * 4;
        QPsh[(qr + 0) * QP8_S + off] = (unsigned char)(p01 & 0xff);
        QPsh[(qr + 1) * QP8_S + off] = (unsigned char)((p01 >> 8) & 0xff);
        QPsh[(qr + 2) * QP8_S + off] = (unsigned char)(p23 & 0xff);
        QPsh[(qr + 3) * QP8_S + off] = (unsigned char)((p23 >> 8) & 0xff);
      }
    }
  }
  __syncthreads();

  // wave w owns PV output d-tile [w*16, w*16+16) for all 64 q
  f32x4 acc[4] = {{0.f, 0.f, 0.f, 0.f}, {0.f, 0.f, 0.f, 0.f},
                  {0.f, 0.f, 0.f, 0.f}, {0.f, 0.f, 0.f, 0.f}};
  float lp[16];
#pragma unroll
  for (int j = 0; j < 16; ++j) lp[j] = 0.f;
  const int kk = w * 16 + l15;
  const bf16* Kbh = Kb + (size_t)bh * TT * 64;
  const bf16* Vtrow = Vt + ((size_t)bh * 64 + w * 16 + l15) * TT;

  // prologue: stage tile 0 operands in registers
  short8 nb0 = *(const short8*)(Kbh + (size_t)kk * 64 + hi * 8);
  short8 nb1 = *(const short8*)(Kbh + (size_t)kk * 64 + 32 + hi * 8);
  short8 nv0 = *(const short8*)(Vtrow + hi * 8);
  short8 nv1 = *(const short8*)(Vtrow + 32 + hi * 8);
  unsigned npm[16];
#pragma unroll
  for (int h = 0; h < 4; ++h)
#pragma unroll
    for (int j = 0; j < 4; ++j)
      npm[h * 4 + j] = pm[(size_t)(qg0 + h * 16 + hi * 4 + j) * TT + kk];

  for (int it = 0; it < 16; ++it) {
    const int k0 = it * 64;
    bf16* PsmC = &Psm[it & 1][0];
    const short8 cb0 = nb0, cb1 = nb1, cv0 = nv0, cv1 = nv1;
    unsigned cpm[16];
#pragma unroll
    for (int j = 0; j < 16; ++j) cpm[j] = npm[j];
    {
      const int k0n = ((it + 1) & 15) * 64;
      nb0 = *(const short8*)(Kbh + (size_t)(k0n + kk) * 64 + hi * 8);
      nb1 = *(const short8*)(Kbh + (size_t)(k0n + kk) * 64 + 32 + hi * 8);
      nv0 = *(const short8*)(Vtrow + k0n + hi * 8);
      nv1 = *(const short8*)(Vtrow + k0n + 32 + hi * 8);
#pragma unroll
      for (int h = 0; h < 4; ++h)
#pragma unroll
        for (int j = 0; j < 4; ++j)
          npm[h * 4 + j] =
              pm[(size_t)(qg0 + h * 16 + hi * 4 + j) * TT + k0n + kk];
    }
    // content scores for 4 q-halves from shared K frags
#pragma unroll
    for (int h = 0; h < 4; ++h) {
      f32x4 s = {0.f, 0.f, 0.f, 0.f};
      s = mfma16(aqA[h], cb0, s);
      s = mfma16(aqB[h], cb1, s);
#pragma unroll
      for (int j = 0; j < 4; ++j) {
        const int q = h * 16 + hi * 4 + j;
        const unsigned pmv = cpm[h * 4 + j];
        const float qp = __builtin_amdgcn_cvt_f32_fp8(
            (int)QPsh[q * QP8_S + (pmv & 0xffffu)], 0);
        const float sv =
            (s[j] + qp + __uint_as_float(pmv & 0xffff0000u)) * 0.125f;
        const float pe = __expf(sv);
        lp[h * 4 + j] += pe;
        PsmC[q * PSM_S + kk] = __float2bfloat16(pe);
      }
    }
    __syncthreads();
    // store P tile (64 q x 64 k) to global, coalesced via LDS
    {
      const int r = tid >> 2, c = (tid & 3) * 16;
      *(short8*)(Pws + ((size_t)(qlocal0 + r) * 64 + bh) * TT + k0 + c) =
          *(const short8*)(PsmC + r * PSM_S + c);
      *(short8*)(Pws + ((size_t)(qlocal0 + r) * 64 + bh) * TT + k0 + c + 8) =
          *(const short8*)(PsmC + r * PSM_S + c + 8);
    }
    // PV MFMAs: wave w's d-tile, 4 q-halves, shared Vt frags
#pragma unroll
    for (int h = 0; h < 4; ++h) {
      const short8 pa0 =
          *(const short8*)(PsmC + (h * 16 + l15) * PSM_S + hi * 8);
      acc[h] = mfma16(pa0, cv0, acc[h]);
      const short8 pa1 =
          *(const short8*)(PsmC + (h * 16 + l15) * PSM_S + 32 + hi * 8);
      acc[h] = mfma16(pa1, cv1, acc[h]);
    }
  }

  // l row-sums: reduce over l15 lanes, then across waves
#pragma unroll
  for (int j = 0; j < 16; ++j) {
    float v = lp[j];
    v += __shfl_xor(v, 1);
    v += __shfl_xor(v, 2);
    v += __shfl_xor(v, 4);
    v += __shfl_xor(v, 8);
    lp[j] = v;
  }
  __syncthreads();
  if (l15 == 0) {
#pragma unroll
    for (int h = 0; h < 4; ++h)
#pragma unroll
      for (int j = 0; j < 4; ++j) lred[w][h * 16 + hi * 4 + j] = lp[h * 4 + j];
  }
  __syncthreads();
  if (tid < 64) {
    const float l = lred[0][tid] + lred[1][tid] + lred[2][tid] + lred[3][tid];
    l_ws[(size_t)bh * TT + qg0 + tid] = l;
  }
  // ctxU scatter: wave w owns d-range [w*16, w*16+16); 64 q rows
  {
    const int b = bh >> 4, h16 = bh & 15;
#pragma unroll
    for (int h = 0; h < 4; ++h)
#pragma unroll
      for (int j = 0; j < 4; ++j) {
        const int q = h * 16 + hi * 4 + j;
        ctxU[((size_t)b * TT + qg0 + q) * DM + h16 * 64 + w * 16 + l15] =
            acc[h][j];
      }
  }
}

// ---------------------------------------------------------------------------
// PV partial kernel (k-split x4): grid (256 q, 4 ks), block 256.
// ---------------------------------------------------------------------------
#define PVT_S 72
__global__ __launch_bounds__(256) void pv_part_kernel(
    const bf16* __restrict__ Pws,
    const float* __restrict__ posV,
    const unsigned* __restrict__ pm,
    float* __restrict__ PP,   // [4][256][64][64] fp32
    int slab) {
  __shared__ __align__(16) bf16 PVt[2][64 * PVT_S];
  __shared__ unsigned short possh[256];

  const int qlocal = blockIdx.x;
  const int q = slab * 256 + qlocal;
  const int ks = blockIdx.y;
  const int kbase = ks * 256;
  const int tid = threadIdx.x;
  const int w = tid >> 6, lane = tid & 63, l15 = lane & 15, hi = lane >> 4;

  possh[tid] = (unsigned short)(pm[(size_t)q * TT + kbase + tid] & 0xffffu);
  __syncthreads();

  f32x4 acc[4] = {{0.f, 0.f, 0.f, 0.f}, {0.f, 0.f, 0.f, 0.f},
                  {0.f, 0.f, 0.f, 0.f}, {0.f, 0.f, 0.f, 0.f}};
  const bf16* Prow = Pws + ((size_t)qlocal * 64 + w * 16 + l15) * TT;

  for (int it = 0; it < 4; ++it) {
    const int k0 = kbase + it * 64;
    bf16* pvt = &PVt[it & 1][0];
    {
      const int kr = lane;
      const int dc = w * 16;
      const int p = possh[it * 64 + kr];
      const float* src = posV + (size_t)p * 64 + dc;
#pragma unroll
      for (int ii = 0; ii < 16; ii += 4) {
        const f32x4 v = *(const f32x4*)(src + ii);
        pvt[(dc + ii + 0) * PVT_S + kr] = __float2bfloat16(v[0]);
        pvt[(dc + ii + 1) * PVT_S + kr] = __float2bfloat16(v[1]);
        pvt[(dc + ii + 2) * PVT_S + kr] = __float2bfloat16(v[2]);
        pvt[(dc + ii + 3) * PVT_S + kr] = __float2bfloat16(v[3]);
      }
    }
    __syncthreads();
#pragma unroll
    for (int kc = 0; kc < 2; ++kc) {
      const short8 a = *(const short8*)(Prow + k0 + kc * 32 + hi * 8);
#pragma unroll
      for (int nt = 0; nt < 4; ++nt) {
        const short8 bv =
            *(const short8*)(pvt + (nt * 16 + l15) * PVT_S + kc * 32 + hi * 8);
        acc[nt] = mfma16(a, bv, acc[nt]);
      }
    }
  }

  const int bh0 = w * 16 + hi * 4;
#pragma unroll
  for (int j = 0; j < 4; ++j) {
    const int bh = bh0 + j;
    float* o = PP + (((size_t)ks * 256 + qlocal) * 64 + bh) * 64;
#pragma unroll
    for (int nt = 0; nt < 4; ++nt) o[nt * 16 + l15] = acc[nt][j];
  }
}

// ---------------------------------------------------------------------------
// Normalize: ctxB = (ctxU + sum_ks PP) / l. grid 1024, block 256.
// ---------------------------------------------------------------------------
__global__ __launch_bounds__(256) void norm_kernel(
    const float* __restrict__ PP,
    const float* __restrict__ ctxU,
    const float* __restrict__ l_ws,
    bf16* __restrict__ ctxB,
    int slab) {
  const int i4 = blockIdx.x * 256 + threadIdx.x;  // 0..262143
  const int e0 = i4 * 4;
  const int dm = e0 & 1023;
  const int qlocal = (e0 >> 10) & 255;
  const int b = e0 >> 18;
  const int h = dm >> 6, d0 = dm & 63;
  const int bh = b * 16 + h;
  const int q = slab * 256 + qlocal;

  f32x4 v = *(const f32x4*)(ctxU + ((size_t)b * TT + q) * DM + dm);
#pragma unroll
  for (int ks = 0; ks < 4; ++ks)
    v += *(const f32x4*)(PP + (((size_t)ks * 256 + qlocal) * 64 + bh) * 64 + d0);
  const float invl = 1.0f / l_ws[(size_t)bh * TT + q];
  bf16 o[4];
#pragma unroll
  for (int j = 0; j < 4; ++j) o[j] = __float2bfloat16(v[j] * invl);
  *(short4v*)(ctxB + ((size_t)b * TT + q) * DM + dm) = *(const short4v*)o;
}

// ---------------------------------------------------------------------------
// Output projection: 128x128 LDS-tiled MFMA GEMM, BK=64, 4 waves (2x2).
// ---------------------------------------------------------------------------
__global__ __launch_bounds__(256) void outproj_mfma_kernel(
    const bf16* __restrict__ A,   // [4096][1024] bf16
    const bf16* __restrict__ Bt,  // [1024 n][1024 k] bf16
    float* __restrict__ C) {
  __shared__ __align__(16) bf16 As[128 * 72];
  __shared__ __align__(16) bf16 Bs[128 * 72];
  const int n0 = blockIdx.x * 128;
  const int m0 = blockIdx.y * 128;
  const int tid = threadIdx.x;
  const int w = tid >> 6, lane = tid & 63, l15 = lane & 15, hi = lane >> 4;
  const int wm = w >> 1, wn = w & 1;

  f32x4 acc[4][4];
#pragma unroll
  for (int i = 0; i < 4; ++i)
#pragma unroll
    for (int j = 0; j < 4; ++j) acc[i][j] = (f32x4){0.f, 0.f, 0.f, 0.f};

  const int sr = tid >> 1, sc = (tid & 1) * 32;
  for (int k0 = 0; k0 < 1024; k0 += 64) {
    __syncthreads();
    {
      const bf16* as = A + (size_t)(m0 + sr) * 1024 + k0 + sc;
      const bf16* bs = Bt + (size_t)(n0 + sr) * 1024 + k0 + sc;
#pragma unroll
      for (int ii = 0; ii < 32; ii += 8) {
        *(short8*)(As + sr * 72 + sc + ii) = *(const short8*)(as + ii);
        *(short8*)(Bs + sr * 72 + sc + ii) = *(const short8*)(bs + ii);
      }
    }
    __syncthreads();
#pragma unroll
    for (int kc = 0; kc < 2; ++kc) {
      short8 a[4], b[4];
#pragma unroll
      for (int i = 0; i < 4; ++i)
        a[i] = *(const short8*)(As + (wm * 64 + i * 16 + l15) * 72 + kc * 32 +
                                hi * 8);
#pragma unroll
      for (int j = 0; j < 4; ++j)
        b[j] = *(const short8*)(Bs + (wn * 64 + j * 16 + l15) * 72 + kc * 32 +
                                hi * 8);
#pragma unroll
      for (int i = 0; i < 4; ++i)
#pragma unroll
        for (int j = 0; j < 4; ++j) acc[i][j] = mfma16(a[i], b[j], acc[i][j]);
    }
  }
#pragma unroll
  for (int i = 0; i < 4; ++i) {
#pragma unroll
    for (int jj = 0; jj < 4; ++jj) {
      const size_t row = (size_t)(m0 + wm * 64 + i * 16 + hi * 4 + jj) * 1024;
#pragma unroll
      for (int j = 0; j < 4; ++j)
        C[row + n0 + wn * 64 + j * 16 + l15] = acc[i][j][jj];
    }
  }
}

// ---------------------------------------------------------------------------
extern "C" void kernel_launch(void* const* d_in, const int* in_sizes, int n_in,
                              void* d_out, int out_size, void* d_ws,
                              size_t ws_size, hipStream_t stream) {
  const float* x = (const float*)d_in[0];
  const float* WQ = (const float*)d_in[1];
  const float* WK = (const float*)d_in[2];
  const float* WV = (const float*)d_in[3];
  const float* WZ = (const float*)d_in[4];
  const float* posK = (const float*)d_in[5];
  const float* posV = (const float*)d_in[6];
  const float* maskp = (const float*)d_in[7];
  const int* pos = (const int*)d_in[8];
  float* out = (float*)d_out;

  char* p = (char*)d_ws;
  bf16* Qb = (bf16*)p;        p += (size_t)64 * 1024 * 64 * 2;   // 8 MB
  bf16* Kb = (bf16*)p;        p += (size_t)64 * 1024 * 64 * 2;   // 8 MB
  bf16* Vb = (bf16*)p;        p += (size_t)64 * 1024 * 64 * 2;   // 8 MB
  bf16* Vt = (bf16*)p;        p += (size_t)64 * 64 * 1024 * 2;   // 8 MB
  bf16* posKbf = (bf16*)p;    p += (size_t)2048 * 64 * 2;        // 256 KB
  bf16* WzT = (bf16*)p;       p += (size_t)1024 * 1024 * 2;      // 2 MB
  bf16* Pws = (bf16*)p;       p += (size_t)256 * 64 * 1024 * 2;  // 32 MB
  float* l_ws = (float*)p;    p += (size_t)64 * 1024 * 4;        // 256 KB
  float* ctxU = (float*)p;    p += (size_t)4 * 1024 * 1024 * 4;  // 16 MB
  bf16* ctxB = (bf16*)p;      p += (size_t)4 * 1024 * 1024 * 2;  // 8 MB
  float* PP = (float*)p;      p += (size_t)4 * 256 * 64 * 64 * 4; // 16 MB
  unsigned* pm_ws = (unsigned*)p; p += (size_t)1024 * 1024 * 4;   // 4 MB

  // Aliases (dead-range reuse, safe under stream ordering):
  bf16* xb = (bf16*)ctxU;  // xb dead after qkv; ctxU written later
  bf16* Wt = ctxB;         // Wt dead after qkv; ctxB written later

  xb_kernel<<<2048, 256, 0, stream>>>(x, xb);
  pack_pm_kernel<<<4096, 256, 0, stream>>>(pos, maskp, pm_ws);
  prep_w_kernel<<<dim3(16, 3), 256, 0, stream>>>(WQ, WK, WV, Wt);
  prep_posk_kernel<<<512, 256, 0, stream>>>(posK, posKbf);
  trans_wz_kernel<<<dim3(16, 16), 256, 0, stream>>>(WZ, WzT);
  qkv_mfma_kernel<<<dim3(16, 64), 256, 0, stream>>>(xb, Wt, Qb, Kb, Vb);
  trans_v_kernel<<<dim3(16, 64), 256, 0, stream>>>(Vb, Vt);

  for (int slab = 0; slab < 4; ++slab) {
    score_pv_kernel<<<dim3(64, 4), 256, 0, stream>>>(
        Qb, Kb, posKbf, Vt, pm_ws, Pws, l_ws, ctxU, slab);
    pv_part_kernel<<<dim3(256, 4), 256, 0, stream>>>(Pws, posV, pm_ws, PP,
                                                     slab);
    norm_kernel<<<1024, 256, 0, stream>>>(PP, ctxU, l_ws, ctxB, slab);
  }
  outproj_mfma_kernel<<<dim3(8, 32), 256, 0, stream>>>(ctxB, WzT, out);
}

// Round 14
// 281.104 us; speedup vs baseline: 1.5902x; 1.0102x over previous
//
#include <hip/hip_runtime.h>
#include <hip/hip_bf16.h>

#define BB 4
#define TT 1024
#define DM 1024
#define HH 16

typedef __attribute__((ext_vector_type(8))) short short8;
typedef __attribute__((ext_vector_type(4))) short short4v;
typedef __attribute__((ext_vector_type(4))) float f32x4;
typedef __hip_bfloat16 bf16;
typedef unsigned char u8;

__device__ __forceinline__ f32x4 mfma16(short8 a, short8 b, f32x4 c) {
  return __builtin_amdgcn_mfma_f32_16x16x32_bf16(a, b, c, 0, 0, 0);
}
__device__ __forceinline__ f32x4 mfma8(long a, long b, f32x4 c) {
  return __builtin_amdgcn_mfma_f32_16x16x32_fp8_fp8(a, b, c, 0, 0, 0);
}

// ---------------------------------------------------------------------------
// x fp32 -> bf16, 8 elems/thread. grid 2048.
// ---------------------------------------------------------------------------
__global__ __launch_bounds__(256) void xb_kernel(
    const float* __restrict__ x, bf16* __restrict__ xb) {
  const size_t i = ((size_t)blockIdx.x * 256 + threadIdx.x) * 8;
  bf16 tmp[8];
#pragma unroll
  for (int j = 0; j < 8; ++j) tmp[j] = __float2bfloat16(x[i + j]);
  *(short8*)(xb + i) = *(const short8*)tmp;
}

// ---------------------------------------------------------------------------
// pack pos (u16, low) + mask (top 16 bits of fp32, high) into one u32.
// ---------------------------------------------------------------------------
__global__ __launch_bounds__(256) void pack_pm_kernel(
    const int* __restrict__ pos, const float* __restrict__ maskp,
    unsigned* __restrict__ pm) {
  const size_t i = (size_t)blockIdx.x * 256 + threadIdx.x;
  const unsigned mb = __float_as_uint(maskp[i]) & 0xffff0000u;
  pm[i] = mb | (unsigned)pos[i];
}

// ---------------------------------------------------------------------------
// W_{Q,K,V} fp32 [16][64 d][64 e] -> Wt bf16 [3][16][64 e][64 d] (transposed)
// ---------------------------------------------------------------------------
__global__ __launch_bounds__(256) void prep_w_kernel(
    const float* __restrict__ WQ, const float* __restrict__ WK,
    const float* __restrict__ WV, bf16* __restrict__ Wt) {
  __shared__ bf16 tl[64][72];
  const int h = blockIdx.x, m = blockIdx.y;
  const float* W = (m == 0 ? WQ : (m == 1 ? WK : WV)) + h * 4096;
  const int tid = threadIdx.x;
  const int r = tid >> 2, c = (tid & 3) * 16;
#pragma unroll
  for (int i = 0; i < 16; ++i)
    tl[r][c + i] = __float2bfloat16(W[r * 64 + c + i]);
  __syncthreads();
  bf16* o = Wt + ((size_t)(m * 16 + h) * 64 + r) * 64 + c;
#pragma unroll
  for (int i = 0; i < 16; ++i) o[i] = tl[c + i][r];
}

// ---------------------------------------------------------------------------
// prep: posK fp32 [2047][64] -> fp8 e4m3 [2048][64] (row 2047 zeroed)
// 2 elems/thread, grid 256.
// ---------------------------------------------------------------------------
__global__ __launch_bounds__(256) void prep_posk8_kernel(
    const float* __restrict__ posK, u8* __restrict__ posK8) {
  const int idx = (blockIdx.x * 256 + threadIdx.x) * 2;
  const int p = idx >> 6, d = idx & 63;
  const float v0 = (p < 2047) ? posK[(size_t)p * 64 + d] : 0.f;
  const float v1 = (p < 2047) ? posK[(size_t)p * 64 + d + 1] : 0.f;
  const int pk = __builtin_amdgcn_cvt_pk_fp8_f32(v0, v1, 0, false);
  *(unsigned short*)(posK8 + idx) = (unsigned short)(pk & 0xffff);
}

// ---------------------------------------------------------------------------
// prep: WzT bf16 [n][k] = Wz fp32 [k][n]
// ---------------------------------------------------------------------------
__global__ __launch_bounds__(256) void trans_wz_kernel(
    const float* __restrict__ Wz, bf16* __restrict__ WzT) {
  __shared__ bf16 tile[64][72];
  const int k0 = blockIdx.y * 64, n0 = blockIdx.x * 64;
  const int tid = threadIdx.x;
  const int r = tid >> 2, c = (tid & 3) * 16;
  const float* s = Wz + (size_t)(k0 + r) * 1024 + n0 + c;
#pragma unroll
  for (int i = 0; i < 16; ++i) tile[r][c + i] = __float2bfloat16(s[i]);
  __syncthreads();
  const int n = tid >> 2;
  bf16* o = WzT + (size_t)(n0 + n) * 1024 + k0 + c;
#pragma unroll
  for (int i = 0; i < 16; ++i) o[i] = tile[c + i][n];
}

// ---------------------------------------------------------------------------
// transpose V: [bh][1024][64] bf16 -> Vt [bh][64][1024] bf16
// ---------------------------------------------------------------------------
__global__ __launch_bounds__(256) void trans_v_kernel(
    const bf16* __restrict__ src, bf16* __restrict__ dst) {
  __shared__ bf16 tile[64][72];
  const int bh = blockIdx.y, t0 = blockIdx.x * 64;
  const int tid = threadIdx.x;
  const int r = tid >> 2, c = (tid & 3) * 16;
  const bf16* s = src + ((size_t)bh * TT + t0 + r) * 64 + c;
  *(short8*)(&tile[r][c]) = *(const short8*)(s);
  *(short8*)(&tile[r][c + 8]) = *(const short8*)(s + 8);
  __syncthreads();
  const int d = tid >> 2;
  bf16* o = dst + ((size_t)bh * 64 + d) * TT + t0 + c;
#pragma unroll
  for (int i = 0; i < 16; ++i) o[i] = tile[c + i][d];
}

// ---------------------------------------------------------------------------
// QKV projection via MFMA. Emits Q8/K8 (fp8 e4m3) + V (bf16).
// grid (16 ttiles, 64 bh), block 256 (4 waves).
// ---------------------------------------------------------------------------
__global__ __launch_bounds__(256) void qkv_mfma_kernel(
    const bf16* __restrict__ xb, const bf16* __restrict__ Wt,
    u8* __restrict__ Q8, u8* __restrict__ K8, bf16* __restrict__ Vg) {
  __shared__ __align__(16) bf16 xs[64 * 72];
  const int bh = blockIdx.y;
  const int b = bh >> 4, h = bh & 15;
  const int t0 = blockIdx.x * 64;
  const int tid = threadIdx.x;
  const int w = tid >> 6, lane = tid & 63, l15 = lane & 15, hi = lane >> 4;

  {
    const int r = tid >> 2, c = (tid & 3) * 16;
    const bf16* src = xb + ((size_t)b * TT + t0 + r) * DM + h * 64 + c;
    *(short8*)(xs + r * 72 + c) = *(const short8*)(src);
    *(short8*)(xs + r * 72 + c + 8) = *(const short8*)(src + 8);
  }
  __syncthreads();

  f32x4 aQ[4] = {{0.f, 0.f, 0.f, 0.f}, {0.f, 0.f, 0.f, 0.f},
                 {0.f, 0.f, 0.f, 0.f}, {0.f, 0.f, 0.f, 0.f}};
  f32x4 aK[4] = {{0.f, 0.f, 0.f, 0.f}, {0.f, 0.f, 0.f, 0.f},
                 {0.f, 0.f, 0.f, 0.f}, {0.f, 0.f, 0.f, 0.f}};
  f32x4 aV[4] = {{0.f, 0.f, 0.f, 0.f}, {0.f, 0.f, 0.f, 0.f},
                 {0.f, 0.f, 0.f, 0.f}, {0.f, 0.f, 0.f, 0.f}};
  const bf16* WtQ = Wt + (size_t)h * 4096;
  const bf16* WtK = Wt + (size_t)(16 + h) * 4096;
  const bf16* WtV = Wt + (size_t)(32 + h) * 4096;
#pragma unroll
  for (int kc = 0; kc < 2; ++kc) {
    const short8 a =
        *(const short8*)(xs + (w * 16 + l15) * 72 + kc * 32 + hi * 8);
#pragma unroll
    for (int nt = 0; nt < 4; ++nt) {
      const size_t wo = (size_t)(nt * 16 + l15) * 64 + kc * 32 + hi * 8;
      aQ[nt] = mfma16(a, *(const short8*)(WtQ + wo), aQ[nt]);
      aK[nt] = mfma16(a, *(const short8*)(WtK + wo), aK[nt]);
      aV[nt] = mfma16(a, *(const short8*)(WtV + wo), aV[nt]);
    }
  }
  const int t = t0 + w * 16 + hi * 4;
#pragma unroll
  for (int nt = 0; nt < 4; ++nt) {
    // V bf16
#pragma unroll
    for (int j = 0; j < 4; ++j) {
      const size_t o = ((size_t)bh * TT + t + j) * 64 + nt * 16 + l15;
      Vg[o] = __float2bfloat16(aV[nt][j]);
    }
    // Q8/K8 fp8 (column byte-stores, stride 64)
    const size_t o0 = ((size_t)bh * TT + t) * 64 + nt * 16 + l15;
    {
      const int p01 = __builtin_amdgcn_cvt_pk_fp8_f32(aQ[nt][0], aQ[nt][1], 0, false);
      const int p23 = __builtin_amdgcn_cvt_pk_fp8_f32(aQ[nt][2], aQ[nt][3], 0, false);
      Q8[o0] = (u8)(p01 & 0xff);
      Q8[o0 + 64] = (u8)((p01 >> 8) & 0xff);
      Q8[o0 + 128] = (u8)(p23 & 0xff);
      Q8[o0 + 192] = (u8)((p23 >> 8) & 0xff);
    }
    {
      const int p01 = __builtin_amdgcn_cvt_pk_fp8_f32(aK[nt][0], aK[nt][1], 0, false);
      const int p23 = __builtin_amdgcn_cvt_pk_fp8_f32(aK[nt][2], aK[nt][3], 0, false);
      K8[o0] = (u8)(p01 & 0xff);
      K8[o0 + 64] = (u8)((p01 >> 8) & 0xff);
      K8[o0 + 128] = (u8)(p23 & 0xff);
      K8[o0 + 192] = (u8)((p23 >> 8) & 0xff);
    }
  }
}

// ---------------------------------------------------------------------------
// Fused score kernel v10: v9 structure, fp8 Q/K/posK operands.
//  Per-block VMEM bytes 784 -> ~588 KB (posK8 128K, K8 64K, pm 256K,
//  Vt 128K, Q8 4K). QP + QK^T use mfma_f32_16x16x32_fp8_fp8 (same lane
//  layout as bf16 K=32 shape; A/B share byte-order -> self-consistent).
// grid (64 bh, 4 qt), block 256 (4 waves), 1 block/CU (150 KB LDS).
// ---------------------------------------------------------------------------
#define QP8_S 2052
#define PSM_S 72

__global__ __launch_bounds__(256, 1) void score_pv_kernel(
    const u8* __restrict__ Q8,
    const u8* __restrict__ K8,
    const u8* __restrict__ posK8,
    const bf16* __restrict__ Vt,
    const unsigned* __restrict__ pm,   // packed mask|pos
    bf16* __restrict__ Pws,        // [256 qlocal][64 bh][1024 k]
    float* __restrict__ l_ws,      // [64 bh][1024 q]
    float* __restrict__ ctxU,      // [b][t][1024] fp32 unnormalized
    int slab) {
  __shared__ __align__(16) u8 QPsh[64 * QP8_S];        // 131328 B
  __shared__ __align__(16) bf16 Psm[2][64 * PSM_S];    // 18432 B
  __shared__ float lred[4][64];                        // 1024 B

  const int bh = blockIdx.x;
  const int qt = blockIdx.y;           // 0..3
  const int qlocal0 = qt * 64;
  const int qg0 = slab * 256 + qlocal0;
  const int tid = threadIdx.x;
  const int w = tid >> 6;
  const int lane = tid & 63;
  const int l15 = lane & 15;
  const int hi = lane >> 4;

  // Q fp8 fragments for 4 q-halves
  long aqA[4], aqB[4];
#pragma unroll
  for (int h = 0; h < 4; ++h) {
    const u8* Qrow =
        Q8 + ((size_t)bh * TT + qg0 + h * 16 + l15) * 64;
    aqA[h] = *(const long*)(Qrow + hi * 8);
    aqB[h] = *(const long*)(Qrow + 32 + hi * 8);
  }

  // ---- QP phase: wave w covers p-tiles w*32..w*32+31; 4 q-halves per
  // posK8 load; fp8 MFMA; fp8 store; 2-stage register pipeline.
  {
    const u8* Kp0 = posK8 + (size_t)(w * 32 * 16 + l15) * 64;
    long qb0 = *(const long*)(Kp0 + hi * 8);
    long qb1 = *(const long*)(Kp0 + 32 + hi * 8);
    for (int i = 0; i < 32; ++i) {
      const int pt = w * 32 + i;
      const long cb0 = qb0, cb1 = qb1;
      {
        const int ptn = w * 32 + ((i + 1) & 31);
        const u8* Kpn = posK8 + (size_t)(ptn * 16 + l15) * 64;
        qb0 = *(const long*)(Kpn + hi * 8);
        qb1 = *(const long*)(Kpn + 32 + hi * 8);
      }
      const int off = pt * 16 + l15;
#pragma unroll
      for (int h = 0; h < 4; ++h) {
        f32x4 a4 = {0.f, 0.f, 0.f, 0.f};
        a4 = mfma8(aqA[h], cb0, a4);
        a4 = mfma8(aqB[h], cb1, a4);
        const int p01 = __builtin_amdgcn_cvt_pk_fp8_f32(a4[0], a4[1], 0, false);
        const int p23 = __builtin_amdgcn_cvt_pk_fp8_f32(a4[2], a4[3], 0, false);
        const int qr = h * 16 + hi * 4;
        QPsh[(qr + 0) * QP8_S + off] = (u8)(p01 & 0xff);
        QPsh[(qr + 1) * QP8_S + off] = (u8)((p01 >> 8) & 0xff);
        QPsh[(qr + 2) * QP8_S + off] = (u8)(p23 & 0xff);
        QPsh[(qr + 3) * QP8_S + off] = (u8)((p23 >> 8) & 0xff);
      }
    }
  }
  __syncthreads();

  // wave w owns PV output d-tile [w*16, w*16+16) for all 64 q
  f32x4 acc[4] = {{0.f, 0.f, 0.f, 0.f}, {0.f, 0.f, 0.f, 0.f},
                  {0.f, 0.f, 0.f, 0.f}, {0.f, 0.f, 0.f, 0.f}};
  float lp[16];
#pragma unroll
  for (int j = 0; j < 16; ++j) lp[j] = 0.f;
  const int kk = w * 16 + l15;
  const u8* K8bh = K8 + (size_t)bh * TT * 64;
  const bf16* Vtrow = Vt + ((size_t)bh * 64 + w * 16 + l15) * TT;

  // prologue: stage tile 0 operands in registers
  long nb0 = *(const long*)(K8bh + (size_t)kk * 64 + hi * 8);
  long nb1 = *(const long*)(K8bh + (size_t)kk * 64 + 32 + hi * 8);
  short8 nv0 = *(const short8*)(Vtrow + hi * 8);
  short8 nv1 = *(const short8*)(Vtrow + 32 + hi * 8);
  unsigned npm[16];
#pragma unroll
  for (int h = 0; h < 4; ++h)
#pragma unroll
    for (int j = 0; j < 4; ++j)
      npm[h * 4 + j] = pm[(size_t)(qg0 + h * 16 + hi * 4 + j) * TT + kk];

  for (int it = 0; it < 16; ++it) {
    const int k0 = it * 64;
    bf16* PsmC = &Psm[it & 1][0];
    const long cb0 = nb0, cb1 = nb1;
    const short8 cv0 = nv0, cv1 = nv1;
    unsigned cpm[16];
#pragma unroll
    for (int j = 0; j < 16; ++j) cpm[j] = npm[j];
    {
      const int k0n = ((it + 1) & 15) * 64;
      nb0 = *(const long*)(K8bh + (size_t)(k0n + kk) * 64 + hi * 8);
      nb1 = *(const long*)(K8bh + (size_t)(k0n + kk) * 64 + 32 + hi * 8);
      nv0 = *(const short8*)(Vtrow + k0n + hi * 8);
      nv1 = *(const short8*)(Vtrow + k0n + 32 + hi * 8);
#pragma unroll
      for (int h = 0; h < 4; ++h)
#pragma unroll
        for (int j = 0; j < 4; ++j)
          npm[h * 4 + j] =
              pm[(size_t)(qg0 + h * 16 + hi * 4 + j) * TT + k0n + kk];
    }
    // content scores for 4 q-halves from shared fp8 K frags
#pragma unroll
    for (int h = 0; h < 4; ++h) {
      f32x4 s = {0.f, 0.f, 0.f, 0.f};
      s = mfma8(aqA[h], cb0, s);
      s = mfma8(aqB[h], cb1, s);
#pragma unroll
      for (int j = 0; j < 4; ++j) {
        const int q = h * 16 + hi * 4 + j;
        const unsigned pmv = cpm[h * 4 + j];
        const float qp = __builtin_amdgcn_cvt_f32_fp8(
            (int)QPsh[q * QP8_S + (pmv & 0xffffu)], 0);
        const float sv =
            (s[j] + qp + __uint_as_float(pmv & 0xffff0000u)) * 0.125f;
        const float pe = __expf(sv);
        lp[h * 4 + j] += pe;
        PsmC[q * PSM_S + kk] = __float2bfloat16(pe);
      }
    }
    __syncthreads();
    // store P tile (64 q x 64 k) to global, coalesced via LDS
    {
      const int r = tid >> 2, c = (tid & 3) * 16;
      *(short8*)(Pws + ((size_t)(qlocal0 + r) * 64 + bh) * TT + k0 + c) =
          *(const short8*)(PsmC + r * PSM_S + c);
      *(short8*)(Pws + ((size_t)(qlocal0 + r) * 64 + bh) * TT + k0 + c + 8) =
          *(const short8*)(PsmC + r * PSM_S + c + 8);
    }
    // PV MFMAs: wave w's d-tile, 4 q-halves, shared Vt frags (bf16)
#pragma unroll
    for (int h = 0; h < 4; ++h) {
      const short8 pa0 =
          *(const short8*)(PsmC + (h * 16 + l15) * PSM_S + hi * 8);
      acc[h] = mfma16(pa0, cv0, acc[h]);
      const short8 pa1 =
          *(const short8*)(PsmC + (h * 16 + l15) * PSM_S + 32 + hi * 8);
      acc[h] = mfma16(pa1, cv1, acc[h]);
    }
  }

  // l row-sums: reduce over l15 lanes, then across waves
#pragma unroll
  for (int j = 0; j < 16; ++j) {
    float v = lp[j];
    v += __shfl_xor(v, 1);
    v += __shfl_xor(v, 2);
    v += __shfl_xor(v, 4);
    v += __shfl_xor(v, 8);
    lp[j] = v;
  }
  __syncthreads();
  if (l15 == 0) {
#pragma unroll
    for (int h = 0; h < 4; ++h)
#pragma unroll
      for (int j = 0; j < 4; ++j) lred[w][h * 16 + hi * 4 + j] = lp[h * 4 + j];
  }
  __syncthreads();
  if (tid < 64) {
    const float l = lred[0][tid] + lred[1][tid] + lred[2][tid] + lred[3][tid];
    l_ws[(size_t)bh * TT + qg0 + tid] = l;
  }
  // ctxU scatter: wave w owns d-range [w*16, w*16+16); 64 q rows
  {
    const int b = bh >> 4, h16 = bh & 15;
#pragma unroll
    for (int h = 0; h < 4; ++h)
#pragma unroll
      for (int j = 0; j < 4; ++j) {
        const int q = h * 16 + hi * 4 + j;
        ctxU[((size_t)b * TT + qg0 + q) * DM + h16 * 64 + w * 16 + l15] =
            acc[h][j];
      }
  }
}

// ---------------------------------------------------------------------------
// PV partial kernel (k-split x4): grid (256 q, 4 ks), block 256.
// ---------------------------------------------------------------------------
#define PVT_S 72
__global__ __launch_bounds__(256) void pv_part_kernel(
    const bf16* __restrict__ Pws,
    const float* __restrict__ posV,
    const unsigned* __restrict__ pm,
    float* __restrict__ PP,   // [4][256][64][64] fp32
    int slab) {
  __shared__ __align__(16) bf16 PVt[2][64 * PVT_S];
  __shared__ unsigned short possh[256];

  const int qlocal = blockIdx.x;
  const int q = slab * 256 + qlocal;
  const int ks = blockIdx.y;
  const int kbase = ks * 256;
  const int tid = threadIdx.x;
  const int w = tid >> 6, lane = tid & 63, l15 = lane & 15, hi = lane >> 4;

  possh[tid] = (unsigned short)(pm[(size_t)q * TT + kbase + tid] & 0xffffu);
  __syncthreads();

  f32x4 acc[4] = {{0.f, 0.f, 0.f, 0.f}, {0.f, 0.f, 0.f, 0.f},
                  {0.f, 0.f, 0.f, 0.f}, {0.f, 0.f, 0.f, 0.f}};
  const bf16* Prow = Pws + ((size_t)qlocal * 64 + w * 16 + l15) * TT;

  for (int it = 0; it < 4; ++it) {
    const int k0 = kbase + it * 64;
    bf16* pvt = &PVt[it & 1][0];
    {
      const int kr = lane;
      const int dc = w * 16;
      const int p = possh[it * 64 + kr];
      const float* src = posV + (size_t)p * 64 + dc;
#pragma unroll
      for (int ii = 0; ii < 16; ii += 4) {
        const f32x4 v = *(const f32x4*)(src + ii);
        pvt[(dc + ii + 0) * PVT_S + kr] = __float2bfloat16(v[0]);
        pvt[(dc + ii + 1) * PVT_S + kr] = __float2bfloat16(v[1]);
        pvt[(dc + ii + 2) * PVT_S + kr] = __float2bfloat16(v[2]);
        pvt[(dc + ii + 3) * PVT_S + kr] = __float2bfloat16(v[3]);
      }
    }
    __syncthreads();
#pragma unroll
    for (int kc = 0; kc < 2; ++kc) {
      const short8 a = *(const short8*)(Prow + k0 + kc * 32 + hi * 8);
#pragma unroll
      for (int nt = 0; nt < 4; ++nt) {
        const short8 bv =
            *(const short8*)(pvt + (nt * 16 + l15) * PVT_S + kc * 32 + hi * 8);
        acc[nt] = mfma16(a, bv, acc[nt]);
      }
    }
  }

  const int bh0 = w * 16 + hi * 4;
#pragma unroll
  for (int j = 0; j < 4; ++j) {
    const int bh = bh0 + j;
    float* o = PP + (((size_t)ks * 256 + qlocal) * 64 + bh) * 64;
#pragma unroll
    for (int nt = 0; nt < 4; ++nt) o[nt * 16 + l15] = acc[nt][j];
  }
}

// ---------------------------------------------------------------------------
// Normalize: ctxB = (ctxU + sum_ks PP) / l. grid 1024, block 256.
// ---------------------------------------------------------------------------
__global__ __launch_bounds__(256) void norm_kernel(
    const float* __restrict__ PP,
    const float* __restrict__ ctxU,
    const float* __restrict__ l_ws,
    bf16* __restrict__ ctxB,
    int slab) {
  const int i4 = blockIdx.x * 256 + threadIdx.x;  // 0..262143
  const int e0 = i4 * 4;
  const int dm = e0 & 1023;
  const int qlocal = (e0 >> 10) & 255;
  const int b = e0 >> 18;
  const int h = dm >> 6, d0 = dm & 63;
  const int bh = b * 16 + h;
  const int q = slab * 256 + qlocal;

  f32x4 v = *(const f32x4*)(ctxU + ((size_t)b * TT + q) * DM + dm);
#pragma unroll
  for (int ks = 0; ks < 4; ++ks)
    v += *(const f32x4*)(PP + (((size_t)ks * 256 + qlocal) * 64 + bh) * 64 + d0);
  const float invl = 1.0f / l_ws[(size_t)bh * TT + q];
  bf16 o[4];
#pragma unroll
  for (int j = 0; j < 4; ++j) o[j] = __float2bfloat16(v[j] * invl);
  *(short4v*)(ctxB + ((size_t)b * TT + q) * DM + dm) = *(const short4v*)o;
}

// ---------------------------------------------------------------------------
// Output projection: 128x128 LDS-tiled MFMA GEMM, BK=64, 4 waves (2x2).
// ---------------------------------------------------------------------------
__global__ __launch_bounds__(256) void outproj_mfma_kernel(
    const bf16* __restrict__ A,   // [4096][1024] bf16
    const bf16* __restrict__ Bt,  // [1024 n][1024 k] bf16
    float* __restrict__ C) {
  __shared__ __align__(16) bf16 As[128 * 72];
  __shared__ __align__(16) bf16 Bs[128 * 72];
  const int n0 = blockIdx.x * 128;
  const int m0 = blockIdx.y * 128;
  const int tid = threadIdx.x;
  const int w = tid >> 6, lane = tid & 63, l15 = lane & 15, hi = lane >> 4;
  const int wm = w >> 1, wn = w & 1;

  f32x4 acc[4][4];
#pragma unroll
  for (int i = 0; i < 4; ++i)
#pragma unroll
    for (int j = 0; j < 4; ++j) acc[i][j] = (f32x4){0.f, 0.f, 0.f, 0.f};

  const int sr = tid >> 1, sc = (tid & 1) * 32;
  for (int k0 = 0; k0 < 1024; k0 += 64) {
    __syncthreads();
    {
      const bf16* as = A + (size_t)(m0 + sr) * 1024 + k0 + sc;
      const bf16* bs = Bt + (size_t)(n0 + sr) * 1024 + k0 + sc;
#pragma unroll
      for (int ii = 0; ii < 32; ii += 8) {
        *(short8*)(As + sr * 72 + sc + ii) = *(const short8*)(as + ii);
        *(short8*)(Bs + sr * 72 + sc + ii) = *(const short8*)(bs + ii);
      }
    }
    __syncthreads();
#pragma unroll
    for (int kc = 0; kc < 2; ++kc) {
      short8 a[4], b[4];
#pragma unroll
      for (int i = 0; i < 4; ++i)
        a[i] = *(const short8*)(As + (wm * 64 + i * 16 + l15) * 72 + kc * 32 +
                                hi * 8);
#pragma unroll
      for (int j = 0; j < 4; ++j)
        b[j] = *(const short8*)(Bs + (wn * 64 + j * 16 + l15) * 72 + kc * 32 +
                                hi * 8);
#pragma unroll
      for (int i = 0; i < 4; ++i)
#pragma unroll
        for (int j = 0; j < 4; ++j) acc[i][j] = mfma16(a[i], b[j], acc[i][j]);
    }
  }
#pragma unroll
  for (int i = 0; i < 4; ++i) {
#pragma unroll
    for (int jj = 0; jj < 4; ++jj) {
      const size_t row = (size_t)(m0 + wm * 64 + i * 16 + hi * 4 + jj) * 1024;
#pragma unroll
      for (int j = 0; j < 4; ++j)
        C[row + n0 + wn * 64 + j * 16 + l15] = acc[i][j][jj];
    }
  }
}

// ---------------------------------------------------------------------------
extern "C" void kernel_launch(void* const* d_in, const int* in_sizes, int n_in,
                              void* d_out, int out_size, void* d_ws,
                              size_t ws_size, hipStream_t stream) {
  const float* x = (const float*)d_in[0];
  const float* WQ = (const float*)d_in[1];
  const float* WK = (const float*)d_in[2];
  const float* WV = (const float*)d_in[3];
  const float* WZ = (const float*)d_in[4];
  const float* posK = (const float*)d_in[5];
  const float* posV = (const float*)d_in[6];
  const float* maskp = (const float*)d_in[7];
  const int* pos = (const int*)d_in[8];
  float* out = (float*)d_out;

  char* p = (char*)d_ws;
  u8* Q8 = (u8*)p;            p += (size_t)64 * 1024 * 64;      // 4 MB
  u8* K8 = (u8*)p;            p += (size_t)64 * 1024 * 64;      // 4 MB
  bf16* Vb = (bf16*)p;        p += (size_t)64 * 1024 * 64 * 2;  // 8 MB
  bf16* Vt = (bf16*)p;        p += (size_t)64 * 64 * 1024 * 2;  // 8 MB
  u8* posK8 = (u8*)p;         p += (size_t)2048 * 64;           // 128 KB
  bf16* WzT = (bf16*)p;       p += (size_t)1024 * 1024 * 2;     // 2 MB
  bf16* Pws = (bf16*)p;       p += (size_t)256 * 64 * 1024 * 2; // 32 MB
  float* l_ws = (float*)p;    p += (size_t)64 * 1024 * 4;       // 256 KB
  float* ctxU = (float*)p;    p += (size_t)4 * 1024 * 1024 * 4; // 16 MB
  bf16* ctxB = (bf16*)p;      p += (size_t)4 * 1024 * 1024 * 2; // 8 MB
  float* PP = (float*)p;      p += (size_t)4 * 256 * 64 * 64 * 4; // 16 MB
  unsigned* pm_ws = (unsigned*)p; p += (size_t)1024 * 1024 * 4;   // 4 MB

  // Aliases (dead-range reuse, safe under stream ordering):
  bf16* xb = (bf16*)ctxU;  // xb dead after qkv; ctxU written later
  bf16* Wt = ctxB;         // Wt dead after qkv; ctxB written later

  xb_kernel<<<2048, 256, 0, stream>>>(x, xb);
  pack_pm_kernel<<<4096, 256, 0, stream>>>(pos, maskp, pm_ws);
  prep_w_kernel<<<dim3(16, 3), 256, 0, stream>>>(WQ, WK, WV, Wt);
  prep_posk8_kernel<<<256, 256, 0, stream>>>(posK, posK8);
  trans_wz_kernel<<<dim3(16, 16), 256, 0, stream>>>(WZ, WzT);
  qkv_mfma_kernel<<<dim3(16, 64), 256, 0, stream>>>(xb, Wt, Q8, K8, Vb);
  trans_v_kernel<<<dim3(16, 64), 256, 0, stream>>>(Vb, Vt);

  for (int slab = 0; slab < 4; ++slab) {
    score_pv_kernel<<<dim3(64, 4), 256, 0, stream>>>(
        Q8, K8, posK8, Vt, pm_ws, Pws, l_ws, ctxU, slab);
    pv_part_kernel<<<dim3(256, 4), 256, 0, stream>>>(Pws, posV, pm_ws, PP,
                                                     slab);
    norm_kernel<<<1024, 256, 0, stream>>>(PP, ctxU, l_ws, ctxB, slab);
  }
  outproj_mfma_kernel<<<dim3(8, 32), 256, 0, stream>>>(ctxB, WzT, out);
}